// Round 5
// baseline (2250.947 us; speedup 1.0000x reference)
//
#include <hip/hip_runtime.h>
#include <math.h>

#define T_  1024
#define D_  512
#define H_  8
#define DK_ 64
#define FF_ 2048
#define BSZ 8
#define M_  (BSZ * T_)   // 8192 rows
#define TP_ (T_ + 4)     // padded rows per batch for causal conv

typedef unsigned short u16;
typedef unsigned int u32;
typedef __attribute__((ext_vector_type(8))) __bf16 bf16x8;
typedef __attribute__((ext_vector_type(4))) float f32x4;

__device__ __forceinline__ u16 f2bf(float f) {            // RNE f32 -> bf16 bits
    unsigned int u = __float_as_uint(f);
    u += 0x7fffu + ((u >> 16) & 1u);
    return (u16)(u >> 16);
}
__device__ __forceinline__ float bf2f(u16 b) {
    return __uint_as_float((unsigned int)b << 16);
}

__device__ __forceinline__ void gload16(const void* g, void* l) {
    // async global->LDS, 16B/lane; LDS dest = wave-uniform base + lane*16
    __builtin_amdgcn_global_load_lds(
        (const __attribute__((address_space(1))) void*)g,
        (__attribute__((address_space(3))) void*)l, 16, 0, 0);
}

// ======================= bf16 MFMA GEMM (m97 structure) =======================
// C[M][N] = A[M][K](bf16) * Bt[N][K]^T(bf16) + bias. 128x128 tile, 4 waves.
// Used for FFN1 (M=8192, N=2048) where the grid is already 1024 blocks.
__global__ void __launch_bounds__(256) gemm_mfma(
    const u16* __restrict__ A, const u16* __restrict__ Bt,
    const float* __restrict__ bias, void* __restrict__ Cout,
    int N, int K, int mode)
{
    __shared__ __align__(16) u16 As[128 * 32];
    __shared__ __align__(16) u16 Bs[128 * 32];
    int tid = threadIdx.x;
    int wid = tid >> 6, lane = tid & 63;
    int quad = lane >> 4, mrow = lane & 15;
    int m0 = blockIdx.y * 128, n0 = blockIdx.x * 128;
    int wr = (wid >> 1) * 64, wc = (wid & 1) * 64;

    const u16* Ap = A + (size_t)(m0 + (tid >> 2)) * K + (tid & 3) * 8;
    const u16* Bp = Bt + (size_t)(n0 + (tid >> 2)) * K + (tid & 3) * 8;
    char* lA = (char*)As + wid * 1024;
    char* lB = (char*)Bs + wid * 1024;

    f32x4 acc[4][4] = {};
    for (int k0 = 0; k0 < K; k0 += 32) {
        __syncthreads();
        gload16(Ap + k0, lA);
        gload16(Ap + (size_t)64 * K + k0, lA + 4096);
        gload16(Bp + k0, lB);
        gload16(Bp + (size_t)64 * K + k0, lB + 4096);
        asm volatile("s_waitcnt vmcnt(0)" ::: "memory");
        __syncthreads();
        bf16x8 af[4], bf[4];
#pragma unroll
        for (int t = 0; t < 4; ++t) {
            af[t] = *(const bf16x8*)&As[(wr + t * 16 + mrow) * 32 + quad * 8];
            bf[t] = *(const bf16x8*)&Bs[(wc + t * 16 + mrow) * 32 + quad * 8];
        }
#pragma unroll
        for (int rt = 0; rt < 4; ++rt)
#pragma unroll
            for (int ct = 0; ct < 4; ++ct)
                acc[rt][ct] = __builtin_amdgcn_mfma_f32_16x16x32_bf16(
                    af[rt], bf[ct], acc[rt][ct], 0, 0, 0);
    }

#pragma unroll
    for (int ct = 0; ct < 4; ++ct) {
        int col = n0 + wc + ct * 16 + mrow;
        float bv = bias ? bias[col] : 0.f;
#pragma unroll
        for (int rt = 0; rt < 4; ++rt) {
            int rowb = m0 + wr + rt * 16 + quad * 4;
            if (mode == 0) {
                float* C = (float*)Cout;
#pragma unroll
                for (int e = 0; e < 4; ++e)
                    C[(size_t)(rowb + e) * N + col] = acc[rt][ct][e] + bv;
            } else if (mode == 1) {
                u16* C = (u16*)Cout;
#pragma unroll
                for (int e = 0; e < 4; ++e)
                    C[(size_t)(rowb + e) * N + col] = f2bf(fmaxf(acc[rt][ct][e] + bv, 0.f));
            } else {
                u16* C = (u16*)Cout;
#pragma unroll
                for (int e = 0; e < 4; ++e)
                    C[(size_t)(rowb + e) * N + col] = f2bf(acc[rt][ct][e] + bv);
            }
        }
    }
}

// ======================= bf16 MFMA GEMM, 64x64 tile (high-occupancy) =======================
// Grid (N/64, M/64) -> 1024+ blocks = 4+ blocks/CU.
// modes: 0 f32; 1 bf16 relu; 2 bf16; 3 per-head-transposed bf16 Vt.
__global__ void __launch_bounds__(256) gemm64_mfma(
    const u16* __restrict__ A, const u16* __restrict__ Bt,
    const float* __restrict__ bias, void* __restrict__ Cout,
    int N, int K, int mode)
{
    __shared__ __align__(16) u16 As[64 * 32];
    __shared__ __align__(16) u16 Bs[64 * 32];
    int tid = threadIdx.x;
    int wid = tid >> 6, lane = tid & 63;
    int quad = lane >> 4, mrow = lane & 15;
    int m0 = blockIdx.y * 64, n0 = blockIdx.x * 64;
    int wc = wid * 16;

    const u16* Ap = A + (size_t)(m0 + (tid >> 2)) * K + (tid & 3) * 8;
    const u16* Bp = Bt + (size_t)(n0 + (tid >> 2)) * K + (tid & 3) * 8;
    char* lA = (char*)As + wid * 1024;
    char* lB = (char*)Bs + wid * 1024;

    f32x4 acc[4] = {};
    for (int k0 = 0; k0 < K; k0 += 32) {
        __syncthreads();
        gload16(Ap + k0, lA);
        gload16(Bp + k0, lB);
        asm volatile("s_waitcnt vmcnt(0)" ::: "memory");
        __syncthreads();
        bf16x8 af[4];
#pragma unroll
        for (int t = 0; t < 4; ++t)
            af[t] = *(const bf16x8*)&As[(t * 16 + mrow) * 32 + quad * 8];
        bf16x8 bf = *(const bf16x8*)&Bs[(wc + mrow) * 32 + quad * 8];
#pragma unroll
        for (int rt = 0; rt < 4; ++rt)
            acc[rt] = __builtin_amdgcn_mfma_f32_16x16x32_bf16(af[rt], bf, acc[rt], 0, 0, 0);
    }

    int col = n0 + wc + mrow;
    float bv = bias ? bias[col] : 0.f;
#pragma unroll
    for (int rt = 0; rt < 4; ++rt) {
        int rowb = m0 + rt * 16 + quad * 4;
        if (mode == 0) {
            float* C = (float*)Cout;
#pragma unroll
            for (int e = 0; e < 4; ++e)
                C[(size_t)(rowb + e) * N + col] = acc[rt][e] + bv;
        } else if (mode == 1) {
            u16* C = (u16*)Cout;
#pragma unroll
            for (int e = 0; e < 4; ++e)
                C[(size_t)(rowb + e) * N + col] = f2bf(fmaxf(acc[rt][e] + bv, 0.f));
        } else if (mode == 2) {
            u16* C = (u16*)Cout;
#pragma unroll
            for (int e = 0; e < 4; ++e)
                C[(size_t)(rowb + e) * N + col] = f2bf(acc[rt][e] + bv);
        } else {
            u16* C = (u16*)Cout;
            int h = col >> 6, dl = col & 63;
#pragma unroll
            for (int e = 0; e < 4; ++e) {
                int row = rowb + e;
                int b = row >> 10, t = row & (T_ - 1);
                C[(((size_t)(b * H_ + h) * DK_ + dl) << 10) + t] =
                    f2bf(acc[rt][e] + bv);
            }
        }
    }
}

// ======================= causal conv1d: 5 shifted passes, 64x64 tile =======================
__global__ void __launch_bounds__(256) conv64_mfma(
    const u16* __restrict__ Xp, const u16* __restrict__ W5t, float* __restrict__ C)
{
    __shared__ __align__(16) u16 As[64 * 32];
    __shared__ __align__(16) u16 Bs[64 * 32];
    int tid = threadIdx.x;
    int wid = tid >> 6, lane = tid & 63;
    int quad = lane >> 4, mrow = lane & 15;
    int m0 = blockIdx.y * 64, n0 = blockIdx.x * 64;
    int wc = wid * 16;
    int b = m0 >> 10, tloc = m0 & (T_ - 1);

    const u16* Ap0 = Xp + (size_t)(b * TP_ + tloc + (tid >> 2)) * D_ + (tid & 3) * 8;
    const u16* Bp0 = W5t + (size_t)(n0 + (tid >> 2)) * D_ + (tid & 3) * 8;
    char* lA = (char*)As + wid * 1024;
    char* lB = (char*)Bs + wid * 1024;

    f32x4 acc[4] = {};
    for (int ks = 0; ks < 5; ++ks) {
        const u16* Ap = Ap0 + ks * D_;
        const u16* Bp = Bp0 + (size_t)ks * D_ * D_;
        for (int k0 = 0; k0 < D_; k0 += 32) {
            __syncthreads();
            gload16(Ap + k0, lA);
            gload16(Bp + k0, lB);
            asm volatile("s_waitcnt vmcnt(0)" ::: "memory");
            __syncthreads();
            bf16x8 af[4];
#pragma unroll
            for (int t = 0; t < 4; ++t)
                af[t] = *(const bf16x8*)&As[(t * 16 + mrow) * 32 + quad * 8];
            bf16x8 bf = *(const bf16x8*)&Bs[(wc + mrow) * 32 + quad * 8];
#pragma unroll
            for (int rt = 0; rt < 4; ++rt)
                acc[rt] = __builtin_amdgcn_mfma_f32_16x16x32_bf16(af[rt], bf, acc[rt], 0, 0, 0);
        }
    }
    int col = n0 + wc + mrow;
#pragma unroll
    for (int rt = 0; rt < 4; ++rt) {
        int row = m0 + rt * 16 + quad * 4;
#pragma unroll
        for (int e = 0; e < 4; ++e)
            C[(size_t)(row + e) * D_ + col] = acc[rt][e];
    }
}

// ======================= QK^T MFMA: S[z][i][k] bf16, causal tiles =======================
__global__ void __launch_bounds__(256) qk_mfma(
    const u16* __restrict__ Qh, u16* __restrict__ S)
{
    int kt = blockIdx.x, it = blockIdx.y;
    if (kt > it) return;
    int z = blockIdx.z;
    int b = z >> 3, h = z & 7;
    __shared__ __align__(16) u16 As[64 * 32];
    __shared__ __align__(16) u16 Bs[64 * 32];
    int tid = threadIdx.x;
    int wid = tid >> 6, lane = tid & 63;
    int quad = lane >> 4, mrow = lane & 15;
    int wc = wid * 16;

    const u16* Ap = Qh + (size_t)(b * T_ + it * 64 + (tid >> 2)) * D_ + h * DK_ + (tid & 3) * 8;
    const u16* Bp = Qh + (size_t)(b * T_ + kt * 64 + (tid >> 2)) * D_ + h * DK_ + (tid & 3) * 8;
    char* lA = (char*)As + wid * 1024;
    char* lB = (char*)Bs + wid * 1024;

    f32x4 acc[4] = {};
#pragma unroll
    for (int k0 = 0; k0 < DK_; k0 += 32) {
        __syncthreads();
        gload16(Ap + k0, lA);
        gload16(Bp + k0, lB);
        asm volatile("s_waitcnt vmcnt(0)" ::: "memory");
        __syncthreads();
        bf16x8 af[4];
#pragma unroll
        for (int t = 0; t < 4; ++t)
            af[t] = *(const bf16x8*)&As[(t * 16 + mrow) * 32 + quad * 8];
        bf16x8 bf = *(const bf16x8*)&Bs[(wc + mrow) * 32 + quad * 8];
#pragma unroll
        for (int rt = 0; rt < 4; ++rt)
            acc[rt] = __builtin_amdgcn_mfma_f32_16x16x32_bf16(af[rt], bf, acc[rt], 0, 0, 0);
    }
    int col = kt * 64 + wc + mrow;
#pragma unroll
    for (int rt = 0; rt < 4; ++rt) {
        int row = it * 64 + rt * 16 + quad * 4;
#pragma unroll
        for (int e = 0; e < 4; ++e)
            S[((size_t)z * T_ + row + e) * T_ + col] = f2bf(acc[rt][e] * 0.125f);
    }
}

// ======================= per-row decay + double softmax =======================
// ONE 256-thread BLOCK per row; thread t owns k in [4t, 4t+4). Per-thread state
// is 12 floats -> fits registers at any occupancy (the old 8-chunk/wave version
// compiled to VGPR=32 + ~5x excess issue slots regardless of launch bounds).
// Cross-thread: in-wave DPP scan + 4-entry LDS combine, 5 barriers per row.
// Masked elements ride through as -1.5e30 (exp2 underflows to exact 0, so
// the final store also writes the zero-fill PV needs).
#define LOG2E 1.4426950408889634f

// update_dpp: lanes with invalid source get OLDB (identity).
#define DPPF(OLDB, X, CTRL, RM) \
    __uint_as_float((u32)__builtin_amdgcn_update_dpp( \
        (int)(OLDB), __float_as_int(X), CTRL, RM, 0xf, false))

__device__ __forceinline__ float scan_add_f(float x) {   // inclusive 64-lane prefix sum
    x += DPPF(0u, x, 0x111, 0xf);   // row_shr:1
    x += DPPF(0u, x, 0x112, 0xf);   // row_shr:2
    x += DPPF(0u, x, 0x114, 0xf);   // row_shr:4
    x += DPPF(0u, x, 0x118, 0xf);   // row_shr:8
    x += DPPF(0u, x, 0x142, 0xa);   // row_bcast:15 -> rows 1,3
    x += DPPF(0u, x, 0x143, 0xc);   // row_bcast:31 -> rows 2,3
    return x;
}
__device__ __forceinline__ float scan_max_f(float x) {   // inclusive 64-lane prefix max
    x = fmaxf(x, DPPF(0xff800000u, x, 0x111, 0xf));
    x = fmaxf(x, DPPF(0xff800000u, x, 0x112, 0xf));
    x = fmaxf(x, DPPF(0xff800000u, x, 0x114, 0xf));
    x = fmaxf(x, DPPF(0xff800000u, x, 0x118, 0xf));
    x = fmaxf(x, DPPF(0xff800000u, x, 0x142, 0xa));
    x = fmaxf(x, DPPF(0xff800000u, x, 0x143, 0xc));
    return x;
}
__device__ __forceinline__ float lane63(float x) {       // broadcast lane 63 (uniform)
    return __uint_as_float((u32)__builtin_amdgcn_readlane(__float_as_int(x), 63));
}

__global__ void __launch_bounds__(256) decay_rows(
    u16* __restrict__ S, const float* __restrict__ gam_l, int mtype)
{
    int tid = threadIdx.x;
    int wv = tid >> 6, lane = tid & 63;
    int i = blockIdx.x;
    int z = blockIdx.y;
    int h = z & 7;
    u16* row = S + ((size_t)z * T_ + i) * T_;
    int kmax = (mtype == 0) ? (i - 1) : i;

    if (kmax < 0) {                     // mtype==0, i==0 (zero_pad row); PV reads k<64
        if (tid < 32) ((u32*)row)[tid] = 0u;
        return;
    }

    __shared__ float l_mx[4], l_t1[4], l_sc[4], l_mx2[4], l_t2[4];

    int k0 = tid * 4;
    int kend_pv = ((i >> 6) + 1) * 64;  // PV reads k < kend_pv for this row

    // ---- load 4 elems (log2e-scaled), mask, per-thread max ----
    ushort4 v = *(const ushort4*)(row + k0);
    float s0 = bf2f(v.x) * LOG2E, s1 = bf2f(v.y) * LOG2E;
    float s2 = bf2f(v.z) * LOG2E, s3 = bf2f(v.w) * LOG2E;
    if (k0     > kmax) s0 = -1.5e30f;
    if (k0 + 1 > kmax) s1 = -1.5e30f;
    if (k0 + 2 > kmax) s2 = -1.5e30f;
    if (k0 + 3 > kmax) s3 = -1.5e30f;

    float m4 = fmaxf(fmaxf(s0, s1), fmaxf(s2, s3));
    float wm = scan_max_f(m4);
    if (lane == 63) l_mx[wv] = wm;
    __syncthreads();
    float mx = fmaxf(fmaxf(l_mx[0], l_mx[1]), fmaxf(l_mx[2], l_mx[3]));

    // ---- softmax #1 (unnormalized) + block cumsum ----
    float p0 = __builtin_amdgcn_exp2f(s0 - mx);
    float p1 = __builtin_amdgcn_exp2f(s1 - mx);
    float p2 = __builtin_amdgcn_exp2f(s2 - mx);
    float p3 = __builtin_amdgcn_exp2f(s3 - mx);
    float t0 = p0, t1 = t0 + p1, t2 = t1 + p2, t3 = t2 + p3;  // in-thread prefix
    float sc = scan_add_f(t3);                                 // in-wave inclusive
    if (lane == 63) l_sc[wv] = sc;
    __syncthreads();
    float tot  = l_sc[0] + l_sc[1] + l_sc[2] + l_sc[3];
    float woff = (wv > 0 ? l_sc[0] : 0.f) + (wv > 1 ? l_sc[1] : 0.f)
               + (wv > 2 ? l_sc[2] : 0.f);
    float off = woff + sc - t3;         // exclusive prefix before this thread
    float inv1 = 1.f / tot;

    // ---- distance effect ----
    float gam = -log1pf(__expf(gam_l[h])) * LOG2E;
    float fi = (float)i;
    float kf = (float)k0;
#define EFFECT(sx, tx, kofs) do {                                           \
        float incl = off + (tx);                                            \
        float rem = fmaxf((tot - incl) * inv1, 0.f);                        \
        float pos = fabsf(kf + (kofs) - fi);                                \
        float ef = __builtin_amdgcn_fmed3f(                                 \
            __builtin_amdgcn_exp2f(sqrtf(rem * pos) * gam), 1e-5f, 1e5f);   \
        (sx) *= ef;                                                         \
    } while (0)
    EFFECT(s0, t0, 0.f);
    EFFECT(s1, t1, 1.f);
    EFFECT(s2, t2, 2.f);
    EFFECT(s3, t3, 3.f);
#undef EFFECT

    // ---- softmax #2 ----
    m4 = fmaxf(fmaxf(s0, s1), fmaxf(s2, s3));
    wm = scan_max_f(m4);
    if (lane == 63) l_mx2[wv] = wm;
    __syncthreads();
    float mx2 = fmaxf(fmaxf(l_mx2[0], l_mx2[1]), fmaxf(l_mx2[2], l_mx2[3]));
    p0 = __builtin_amdgcn_exp2f(s0 - mx2);
    p1 = __builtin_amdgcn_exp2f(s1 - mx2);
    p2 = __builtin_amdgcn_exp2f(s2 - mx2);
    p3 = __builtin_amdgcn_exp2f(s3 - mx2);
    float q4 = (p0 + p1) + (p2 + p3);
    float ws = scan_add_f(q4);
    if (lane == 63) l_t2[wv] = ws;
    __syncthreads();
    float tot2 = l_t2[0] + l_t2[1] + l_t2[2] + l_t2[3];
    float inv2 = 1.f / tot2;

    // ---- write P (2x v_cvt_pk_bf16_f32, 8B store); masked elems store 0 ----
    if (k0 < kend_pv) {
        float a0 = p0 * inv2, a1 = p1 * inv2, a2 = p2 * inv2, a3 = p3 * inv2;
        u32 o0, o1;
        asm("v_cvt_pk_bf16_f32 %0, %1, %2" : "=v"(o0) : "v"(a0), "v"(a1));
        asm("v_cvt_pk_bf16_f32 %0, %1, %2" : "=v"(o1) : "v"(a2), "v"(a3));
        uint2 o; o.x = o0; o.y = o1;
        *(uint2*)(row + k0) = o;
    }
}

// ======================= PV MFMA: O = P(bf16) x V, causal K-bound =======================
__global__ void __launch_bounds__(256) pv_mfma(
    const u16* __restrict__ P, const u16* __restrict__ Vt,
    u16* __restrict__ O)
{
    int mt = blockIdx.x;
    int z = blockIdx.y;
    int b = z >> 3, h = z & 7;
    __shared__ __align__(16) u16 As[64 * 32];
    __shared__ __align__(16) u16 Bs[64 * 32];
    int tid = threadIdx.x;
    int wid = tid >> 6, lane = tid & 63;
    int quad = lane >> 4, mrow = lane & 15;
    int wc = wid * 16;

    const u16* Ap = P + ((size_t)z * T_ + mt * 64 + (tid >> 2)) * T_ + (tid & 3) * 8;
    const u16* Bp = Vt + ((size_t)z * DK_ + (tid >> 2)) * T_ + (tid & 3) * 8;
    char* lA = (char*)As + wid * 1024;
    char* lB = (char*)Bs + wid * 1024;

    int kend = (mt + 1) * 64;
    f32x4 acc[4] = {};
    for (int k0 = 0; k0 < kend; k0 += 32) {
        __syncthreads();
        gload16(Ap + k0, lA);
        gload16(Bp + k0, lB);
        asm volatile("s_waitcnt vmcnt(0)" ::: "memory");
        __syncthreads();
        bf16x8 af[4];
#pragma unroll
        for (int t = 0; t < 4; ++t)
            af[t] = *(const bf16x8*)&As[(t * 16 + mrow) * 32 + quad * 8];
        bf16x8 bf = *(const bf16x8*)&Bs[(wc + mrow) * 32 + quad * 8];
#pragma unroll
        for (int rt = 0; rt < 4; ++rt)
            acc[rt] = __builtin_amdgcn_mfma_f32_16x16x32_bf16(af[rt], bf, acc[rt], 0, 0, 0);
    }
    int col = h * DK_ + wc + mrow;
#pragma unroll
    for (int rt = 0; rt < 4; ++rt) {
        int row = b * T_ + mt * 64 + rt * 16 + quad * 4;
#pragma unroll
        for (int e = 0; e < 4; ++e)
            O[(size_t)(row + e) * D_ + col] = f2bf(acc[rt][e]);
    }
}

// ======================= prep kernels =======================
__global__ void __launch_bounds__(256) transpose_bf16(
    const float* __restrict__ W, u16* __restrict__ Wt, int K, int N)
{
    __shared__ float tile[32][33];
    size_t base = (size_t)blockIdx.z * K * N;
    W += base; Wt += base;
    int k0 = blockIdx.y * 32, n0 = blockIdx.x * 32;
    int r = threadIdx.x >> 3, c = (threadIdx.x & 7) * 4;
    float4 v = *(const float4*)(W + (size_t)(k0 + r) * N + n0 + c);
    tile[r][c] = v.x; tile[r][c + 1] = v.y; tile[r][c + 2] = v.z; tile[r][c + 3] = v.w;
    __syncthreads();
    ushort4 o;
    o.x = f2bf(tile[c + 0][r]); o.y = f2bf(tile[c + 1][r]);
    o.z = f2bf(tile[c + 2][r]); o.w = f2bf(tile[c + 3][r]);
    *(ushort4*)(Wt + (size_t)(n0 + r) * K + k0 + c) = o;
}

__global__ void w5_gather(const float* __restrict__ cw, u16* __restrict__ W5t)
{
    int idx = blockIdx.x * 256 + threadIdx.x;
    if (idx >= 5 * D_ * D_) return;
    int ks = idx / (D_ * D_);
    int rem = idx - ks * (D_ * D_);
    int o = rem >> 9, i = rem & (D_ - 1);
    W5t[idx] = f2bf(cw[((size_t)o * D_ + i) * 5 + ks]);
}

__global__ void cast_pad(const float* __restrict__ x, const float* __restrict__ y,
                         u16* __restrict__ Xp, u16* __restrict__ Yp)
{
    int idx = blockIdx.x * 256 + threadIdx.x;
    if (idx >= BSZ * TP_ * D_) return;
    int d = idx & (D_ - 1);
    int rowp = idx >> 9;
    int b = rowp / TP_;
    int t = rowp - b * TP_;
    u16 vx = 0, vy = 0;
    if (t >= 4) {
        size_t src = ((size_t)(b * T_ + t - 4) << 9) + d;
        vx = f2bf(x[src]); vy = f2bf(y[src]);
    }
    Xp[idx] = vx; Yp[idx] = vy;
}

// ======================= smooth pointwise + LayerNorm (eps=1e-12) =======================
__global__ void __launch_bounds__(256) smooth_ln(
    const float* __restrict__ x, const float* __restrict__ trend,
    const float* __restrict__ conv_b, const float* __restrict__ sqrt_beta,
    const float* __restrict__ g, const float* __restrict__ bb,
    float* __restrict__ out, u16* __restrict__ outb)
{
    __shared__ float s_red[8];
    int row = blockIdx.x, tid = threadIdx.x;
    int lane = tid & 63, wid = tid >> 6;
    float2 xv = ((const float2*)(x + (size_t)row * D_))[tid];
    float2 tv = ((const float2*)(trend + (size_t)row * D_))[tid];
    float2 cb = ((const float2*)conv_b)[tid];
    float2 sb = ((const float2*)sqrt_beta)[tid];
    float t0 = tv.x + cb.x, t1 = tv.y + cb.y;
    float v0 = t0 + sb.x * sb.x * (xv.x - t0) + xv.x;
    float v1 = t1 + sb.y * sb.y * (xv.y - t1) + xv.y;
    float s = v0 + v1, sq = v0 * v0 + v1 * v1;
    for (int o = 32; o > 0; o >>= 1) { s += __shfl_xor(s, o, 64); sq += __shfl_xor(sq, o, 64); }
    if (lane == 0) { s_red[wid] = s; s_red[4 + wid] = sq; }
    __syncthreads();
    s = s_red[0] + s_red[1] + s_red[2] + s_red[3];
    sq = s_red[4] + s_red[5] + s_red[6] + s_red[7];
    float mean = s * (1.f / D_);
    float var = sq * (1.f / D_) - mean * mean;
    if (var < 0.f) var = 0.f;
    float rstd = rsqrtf(var + 1e-12f);
    float2 gv = ((const float2*)g)[tid];
    float2 bv = ((const float2*)bb)[tid];
    float2 o2;
    o2.x = gv.x * (v0 - mean) * rstd + bv.x;
    o2.y = gv.y * (v1 - mean) * rstd + bv.y;
    ((float2*)(out + (size_t)row * D_))[tid] = o2;
    ushort2 ob; ob.x = f2bf(o2.x); ob.y = f2bf(o2.y);
    ((ushort2*)(outb + (size_t)row * D_))[tid] = ob;
}

// ======================= residual add + LayerNorm (f32 + bf16 out) =======================
__global__ void __launch_bounds__(256) add_ln(
    const float* __restrict__ a, const float* __restrict__ c,
    const float* __restrict__ g, const float* __restrict__ bb,
    float* __restrict__ out, u16* __restrict__ outb, float eps)
{
    __shared__ float s_red[8];
    int row = blockIdx.x, tid = threadIdx.x;
    int lane = tid & 63, wid = tid >> 6;
    float2 av = ((const float2*)(a + (size_t)row * D_))[tid];
    float2 cv = ((const float2*)(c + (size_t)row * D_))[tid];
    float v0 = av.x + cv.x;
    float v1 = av.y + cv.y;
    float s = v0 + v1, sq = v0 * v0 + v1 * v1;
    for (int o = 32; o > 0; o >>= 1) { s += __shfl_xor(s, o, 64); sq += __shfl_xor(sq, o, 64); }
    if (lane == 0) { s_red[wid] = s; s_red[4 + wid] = sq; }
    __syncthreads();
    s = s_red[0] + s_red[1] + s_red[2] + s_red[3];
    sq = s_red[4] + s_red[5] + s_red[6] + s_red[7];
    float mean = s * (1.f / D_);
    float var = sq * (1.f / D_) - mean * mean;
    if (var < 0.f) var = 0.f;
    float rstd = rsqrtf(var + eps);
    float2 gv = ((const float2*)g)[tid];
    float2 bv = ((const float2*)bb)[tid];
    float2 o2;
    o2.x = gv.x * (v0 - mean) * rstd + bv.x;
    o2.y = gv.y * (v1 - mean) * rstd + bv.y;
    ((float2*)(out + (size_t)row * D_))[tid] = o2;
    ushort2 ob; ob.x = f2bf(o2.x); ob.y = f2bf(o2.y);
    ((ushort2*)(outb + (size_t)row * D_))[tid] = ob;
}

// ======================= launch =======================
extern "C" void kernel_launch(void* const* d_in, const int* in_sizes, int n_in,
                              void* d_out, int out_size, void* d_ws, size_t ws_size,
                              hipStream_t stream)
{
    const float* q_embed   = (const float*)d_in[0];
    const float* qa_embed  = (const float*)d_in[1];
    const float* conv_w    = (const float*)d_in[3];
    const float* conv_b    = (const float*)d_in[4];
    const float* sqrt_beta = (const float*)d_in[5];
    const float* sm_g      = (const float*)d_in[6];
    const float* sm_b      = (const float*)d_in[7];
    const float* k_w       = (const float*)d_in[8];
    const float* k_b       = (const float*)d_in[9];
    const float* v_w       = (const float*)d_in[10];
    const float* v_b       = (const float*)d_in[11];
    const float* out_w     = (const float*)d_in[12];
    const float* out_b     = (const float*)d_in[13];
    const float* gammas    = (const float*)d_in[14];
    const float* ln1_g     = (const float*)d_in[15];
    const float* ln1_b     = (const float*)d_in[16];
    const float* ff1_w     = (const float*)d_in[17];
    const float* ff1_b     = (const float*)d_in[18];
    const float* ff2_w     = (const float*)d_in[19];
    const float* ff2_b     = (const float*)d_in[20];
    const float* ln2_g     = (const float*)d_in[21];
    const float* ln2_b     = (const float*)d_in[22];

    const size_t NT = (size_t)M_ * D_;
    float* X = (float*)d_out;
    char* w = (char*)d_ws;
    float* Y  = (float*)w; w += NT * 4;          // 16 MB
    float* Fb = (float*)w; w += NT * 4;          // 16 MB
    u16* Sb = (u16*)w;                           // scores/P bf16: 128 MB
    u16* Hb = Sb;                                // aliases: ffn hidden bf16 (32 MB)
    u16* Xpad = Sb;                              // aliases: prep buffers
    u16* Ypad = Xpad + (size_t)BSZ * TP_ * D_;
    u16* W5t  = Ypad + (size_t)BSZ * TP_ * D_;
    w += (size_t)BSZ * H_ * T_ * T_ * 2;
    u16* Xb  = (u16*)w; w += NT * 2;
    u16* Yb  = (u16*)w; w += NT * 2;
    u16* Cb  = (u16*)w; w += NT * 2;
    u16* Qh  = (u16*)w; w += NT * 2;
    u16* Vt  = (u16*)w; w += NT * 2;
    u16* KWt = (u16*)w; w += (size_t)6 * D_ * D_ * 2;
    u16* VWt = (u16*)w; w += (size_t)6 * D_ * D_ * 2;
    u16* OWt = (u16*)w; w += (size_t)6 * D_ * D_ * 2;
    u16* F1t = (u16*)w; w += (size_t)6 * D_ * FF_ * 2;
    u16* F2t = (u16*)w; w += (size_t)6 * FF_ * D_ * 2;

    dim3 blk(256);

    // ---- prep ----
    cast_pad<<<(BSZ * TP_ * D_ + 255) / 256, blk, 0, stream>>>(q_embed, qa_embed, Xpad, Ypad);
    w5_gather<<<(5 * D_ * D_ + 255) / 256, blk, 0, stream>>>(conv_w, W5t);
    transpose_bf16<<<dim3(D_ / 32, D_ / 32, 6), blk, 0, stream>>>(k_w, KWt, D_, D_);
    transpose_bf16<<<dim3(D_ / 32, D_ / 32, 6), blk, 0, stream>>>(v_w, VWt, D_, D_);
    transpose_bf16<<<dim3(D_ / 32, D_ / 32, 6), blk, 0, stream>>>(out_w, OWt, D_, D_);
    transpose_bf16<<<dim3(FF_ / 32, D_ / 32, 6), blk, 0, stream>>>(ff1_w, F1t, D_, FF_);
    transpose_bf16<<<dim3(D_ / 32, FF_ / 32, 6), blk, 0, stream>>>(ff2_w, F2t, FF_, D_);

    // ---- smooth(x), smooth(y) ----  (64-tile conv: 1024 blocks = 4/CU)
    conv64_mfma<<<dim3(8, 128), blk, 0, stream>>>(Xpad, W5t, Fb);
    smooth_ln<<<M_, blk, 0, stream>>>(q_embed, Fb, conv_b, sqrt_beta, sm_g, sm_b, X, Xb);
    conv64_mfma<<<dim3(8, 128), blk, 0, stream>>>(Ypad, W5t, Fb);
    smooth_ln<<<M_, blk, 0, stream>>>(qa_embed, Fb, conv_b, sqrt_beta, sm_g, sm_b, Y, Yb);

    auto layer = [&](int l, int mtype, float* io, u16* iob, const u16* vinb, bool ffn) {
        gemm64_mfma<<<dim3(8, 128), blk, 0, stream>>>(iob, KWt + (size_t)l * D_ * D_,
                                                      k_b + (size_t)l * D_, Qh, D_, D_, 2);
        gemm64_mfma<<<dim3(8, 128), blk, 0, stream>>>(vinb, VWt + (size_t)l * D_ * D_,
                                                      v_b + (size_t)l * D_, Vt, D_, D_, 3);
        qk_mfma<<<dim3(16, 16, 64), blk, 0, stream>>>(Qh, Sb);
        decay_rows<<<dim3(T_, 64), blk, 0, stream>>>(Sb, gammas + l * H_, mtype);
        pv_mfma<<<dim3(16, 64), blk, 0, stream>>>(Sb, Vt, Cb);
        gemm64_mfma<<<dim3(8, 128), blk, 0, stream>>>(Cb, OWt + (size_t)l * D_ * D_,
                                                      out_b + (size_t)l * D_, Fb, D_, D_, 0);
        add_ln<<<M_, blk, 0, stream>>>(io, Fb, ln1_g + l * D_, ln1_b + l * D_, io, iob, 1e-5f);
        if (ffn) {
            gemm_mfma<<<dim3(16, 64), blk, 0, stream>>>(iob, F1t + (size_t)l * D_ * FF_,
                                                        ff1_b + (size_t)l * FF_, Hb, FF_, D_, 1);
            gemm64_mfma<<<dim3(8, 128), blk, 0, stream>>>(Hb, F2t + (size_t)l * FF_ * D_,
                                                          ff2_b + (size_t)l * D_, Fb, D_, FF_, 0);
            add_ln<<<M_, blk, 0, stream>>>(io, Fb, ln2_g + l * D_, ln2_b + l * D_, io, iob, 1e-5f);
        }
    };

    layer(0, 1, Y, Yb, Yb, true);
    layer(1, 1, Y, Yb, Yb, true);
    layer(2, 1, X, Xb, Xb, false);
    layer(3, 0, X, Xb, Yb, true);
    layer(4, 1, X, Xb, Xb, false);
    layer(5, 0, X, Xb, Yb, true);
}

// Round 6
// 1804.702 us; speedup vs baseline: 1.2473x; 1.2473x over previous
//
#include <hip/hip_runtime.h>
#include <math.h>

#define T_  1024
#define D_  512
#define H_  8
#define DK_ 64
#define FF_ 2048
#define BSZ 8
#define M_  (BSZ * T_)   // 8192 rows
#define TP_ (T_ + 4)     // padded rows per batch for causal conv

typedef unsigned short u16;
typedef unsigned int u32;
typedef __attribute__((ext_vector_type(8))) __bf16 bf16x8;
typedef __attribute__((ext_vector_type(4))) float f32x4;

__device__ __forceinline__ u16 f2bf(float f) {            // RNE f32 -> bf16 bits
    unsigned int u = __float_as_uint(f);
    u += 0x7fffu + ((u >> 16) & 1u);
    return (u16)(u >> 16);
}
__device__ __forceinline__ float bf2f(u16 b) {
    return __uint_as_float((unsigned int)b << 16);
}

__device__ __forceinline__ void gload16(const void* g, void* l) {
    // async global->LDS, 16B/lane; LDS dest = wave-uniform base + lane*16
    __builtin_amdgcn_global_load_lds(
        (const __attribute__((address_space(1))) void*)g,
        (__attribute__((address_space(3))) void*)l, 16, 0, 0);
}

// ======================= bf16 MFMA GEMM (m97 structure) =======================
// C[M][N] = A[M][K](bf16) * Bt[N][K]^T(bf16) + bias. 128x128 tile, 4 waves.
// Used for FFN1 (M=8192, N=2048) where the grid is already 1024 blocks.
__global__ void __launch_bounds__(256) gemm_mfma(
    const u16* __restrict__ A, const u16* __restrict__ Bt,
    const float* __restrict__ bias, void* __restrict__ Cout,
    int N, int K, int mode)
{
    __shared__ __align__(16) u16 As[128 * 32];
    __shared__ __align__(16) u16 Bs[128 * 32];
    int tid = threadIdx.x;
    int wid = tid >> 6, lane = tid & 63;
    int quad = lane >> 4, mrow = lane & 15;
    int m0 = blockIdx.y * 128, n0 = blockIdx.x * 128;
    int wr = (wid >> 1) * 64, wc = (wid & 1) * 64;

    const u16* Ap = A + (size_t)(m0 + (tid >> 2)) * K + (tid & 3) * 8;
    const u16* Bp = Bt + (size_t)(n0 + (tid >> 2)) * K + (tid & 3) * 8;
    char* lA = (char*)As + wid * 1024;
    char* lB = (char*)Bs + wid * 1024;

    f32x4 acc[4][4] = {};
    for (int k0 = 0; k0 < K; k0 += 32) {
        __syncthreads();
        gload16(Ap + k0, lA);
        gload16(Ap + (size_t)64 * K + k0, lA + 4096);
        gload16(Bp + k0, lB);
        gload16(Bp + (size_t)64 * K + k0, lB + 4096);
        asm volatile("s_waitcnt vmcnt(0)" ::: "memory");
        __syncthreads();
        bf16x8 af[4], bf[4];
#pragma unroll
        for (int t = 0; t < 4; ++t) {
            af[t] = *(const bf16x8*)&As[(wr + t * 16 + mrow) * 32 + quad * 8];
            bf[t] = *(const bf16x8*)&Bs[(wc + t * 16 + mrow) * 32 + quad * 8];
        }
#pragma unroll
        for (int rt = 0; rt < 4; ++rt)
#pragma unroll
            for (int ct = 0; ct < 4; ++ct)
                acc[rt][ct] = __builtin_amdgcn_mfma_f32_16x16x32_bf16(
                    af[rt], bf[ct], acc[rt][ct], 0, 0, 0);
    }

#pragma unroll
    for (int ct = 0; ct < 4; ++ct) {
        int col = n0 + wc + ct * 16 + mrow;
        float bv = bias ? bias[col] : 0.f;
#pragma unroll
        for (int rt = 0; rt < 4; ++rt) {
            int rowb = m0 + wr + rt * 16 + quad * 4;
            if (mode == 0) {
                float* C = (float*)Cout;
#pragma unroll
                for (int e = 0; e < 4; ++e)
                    C[(size_t)(rowb + e) * N + col] = acc[rt][ct][e] + bv;
            } else if (mode == 1) {
                u16* C = (u16*)Cout;
#pragma unroll
                for (int e = 0; e < 4; ++e)
                    C[(size_t)(rowb + e) * N + col] = f2bf(fmaxf(acc[rt][ct][e] + bv, 0.f));
            } else {
                u16* C = (u16*)Cout;
#pragma unroll
                for (int e = 0; e < 4; ++e)
                    C[(size_t)(rowb + e) * N + col] = f2bf(acc[rt][ct][e] + bv);
            }
        }
    }
}

// ======================= bf16 MFMA GEMM, 64x64 tile (high-occupancy) =======================
// Grid (N/64, M/64) -> 1024+ blocks = 4+ blocks/CU.
// modes: 0 f32; 1 bf16 relu; 2 bf16; 3 per-head-transposed bf16 Vt.
__global__ void __launch_bounds__(256) gemm64_mfma(
    const u16* __restrict__ A, const u16* __restrict__ Bt,
    const float* __restrict__ bias, void* __restrict__ Cout,
    int N, int K, int mode)
{
    __shared__ __align__(16) u16 As[64 * 32];
    __shared__ __align__(16) u16 Bs[64 * 32];
    int tid = threadIdx.x;
    int wid = tid >> 6, lane = tid & 63;
    int quad = lane >> 4, mrow = lane & 15;
    int m0 = blockIdx.y * 64, n0 = blockIdx.x * 64;
    int wc = wid * 16;

    const u16* Ap = A + (size_t)(m0 + (tid >> 2)) * K + (tid & 3) * 8;
    const u16* Bp = Bt + (size_t)(n0 + (tid >> 2)) * K + (tid & 3) * 8;
    char* lA = (char*)As + wid * 1024;
    char* lB = (char*)Bs + wid * 1024;

    f32x4 acc[4] = {};
    for (int k0 = 0; k0 < K; k0 += 32) {
        __syncthreads();
        gload16(Ap + k0, lA);
        gload16(Bp + k0, lB);
        asm volatile("s_waitcnt vmcnt(0)" ::: "memory");
        __syncthreads();
        bf16x8 af[4];
#pragma unroll
        for (int t = 0; t < 4; ++t)
            af[t] = *(const bf16x8*)&As[(t * 16 + mrow) * 32 + quad * 8];
        bf16x8 bf = *(const bf16x8*)&Bs[(wc + mrow) * 32 + quad * 8];
#pragma unroll
        for (int rt = 0; rt < 4; ++rt)
            acc[rt] = __builtin_amdgcn_mfma_f32_16x16x32_bf16(af[rt], bf, acc[rt], 0, 0, 0);
    }

    int col = n0 + wc + mrow;
    float bv = bias ? bias[col] : 0.f;
#pragma unroll
    for (int rt = 0; rt < 4; ++rt) {
        int rowb = m0 + rt * 16 + quad * 4;
        if (mode == 0) {
            float* C = (float*)Cout;
#pragma unroll
            for (int e = 0; e < 4; ++e)
                C[(size_t)(rowb + e) * N + col] = acc[rt][e] + bv;
        } else if (mode == 1) {
            u16* C = (u16*)Cout;
#pragma unroll
            for (int e = 0; e < 4; ++e)
                C[(size_t)(rowb + e) * N + col] = f2bf(fmaxf(acc[rt][e] + bv, 0.f));
        } else if (mode == 2) {
            u16* C = (u16*)Cout;
#pragma unroll
            for (int e = 0; e < 4; ++e)
                C[(size_t)(rowb + e) * N + col] = f2bf(acc[rt][e] + bv);
        } else {
            u16* C = (u16*)Cout;
            int h = col >> 6, dl = col & 63;
#pragma unroll
            for (int e = 0; e < 4; ++e) {
                int row = rowb + e;
                int b = row >> 10, t = row & (T_ - 1);
                C[(((size_t)(b * H_ + h) * DK_ + dl) << 10) + t] =
                    f2bf(acc[rt][e] + bv);
            }
        }
    }
}

// ======================= causal conv1d: 5 shifted passes, 64x64 tile =======================
__global__ void __launch_bounds__(256) conv64_mfma(
    const u16* __restrict__ Xp, const u16* __restrict__ W5t, float* __restrict__ C)
{
    __shared__ __align__(16) u16 As[64 * 32];
    __shared__ __align__(16) u16 Bs[64 * 32];
    int tid = threadIdx.x;
    int wid = tid >> 6, lane = tid & 63;
    int quad = lane >> 4, mrow = lane & 15;
    int m0 = blockIdx.y * 64, n0 = blockIdx.x * 64;
    int wc = wid * 16;
    int b = m0 >> 10, tloc = m0 & (T_ - 1);

    const u16* Ap0 = Xp + (size_t)(b * TP_ + tloc + (tid >> 2)) * D_ + (tid & 3) * 8;
    const u16* Bp0 = W5t + (size_t)(n0 + (tid >> 2)) * D_ + (tid & 3) * 8;
    char* lA = (char*)As + wid * 1024;
    char* lB = (char*)Bs + wid * 1024;

    f32x4 acc[4] = {};
    for (int ks = 0; ks < 5; ++ks) {
        const u16* Ap = Ap0 + ks * D_;
        const u16* Bp = Bp0 + (size_t)ks * D_ * D_;
        for (int k0 = 0; k0 < D_; k0 += 32) {
            __syncthreads();
            gload16(Ap + k0, lA);
            gload16(Bp + k0, lB);
            asm volatile("s_waitcnt vmcnt(0)" ::: "memory");
            __syncthreads();
            bf16x8 af[4];
#pragma unroll
            for (int t = 0; t < 4; ++t)
                af[t] = *(const bf16x8*)&As[(t * 16 + mrow) * 32 + quad * 8];
            bf16x8 bf = *(const bf16x8*)&Bs[(wc + mrow) * 32 + quad * 8];
#pragma unroll
            for (int rt = 0; rt < 4; ++rt)
                acc[rt] = __builtin_amdgcn_mfma_f32_16x16x32_bf16(af[rt], bf, acc[rt], 0, 0, 0);
        }
    }
    int col = n0 + wc + mrow;
#pragma unroll
    for (int rt = 0; rt < 4; ++rt) {
        int row = m0 + rt * 16 + quad * 4;
#pragma unroll
        for (int e = 0; e < 4; ++e)
            C[(size_t)(row + e) * D_ + col] = acc[rt][e];
    }
}

// ======================= QK^T MFMA: S[z][i][k] bf16, causal tiles =======================
__global__ void __launch_bounds__(256) qk_mfma(
    const u16* __restrict__ Qh, u16* __restrict__ S)
{
    int kt = blockIdx.x, it = blockIdx.y;
    if (kt > it) return;
    int z = blockIdx.z;
    int b = z >> 3, h = z & 7;
    __shared__ __align__(16) u16 As[64 * 32];
    __shared__ __align__(16) u16 Bs[64 * 32];
    int tid = threadIdx.x;
    int wid = tid >> 6, lane = tid & 63;
    int quad = lane >> 4, mrow = lane & 15;
    int wc = wid * 16;

    const u16* Ap = Qh + (size_t)(b * T_ + it * 64 + (tid >> 2)) * D_ + h * DK_ + (tid & 3) * 8;
    const u16* Bp = Qh + (size_t)(b * T_ + kt * 64 + (tid >> 2)) * D_ + h * DK_ + (tid & 3) * 8;
    char* lA = (char*)As + wid * 1024;
    char* lB = (char*)Bs + wid * 1024;

    f32x4 acc[4] = {};
#pragma unroll
    for (int k0 = 0; k0 < DK_; k0 += 32) {
        __syncthreads();
        gload16(Ap + k0, lA);
        gload16(Bp + k0, lB);
        asm volatile("s_waitcnt vmcnt(0)" ::: "memory");
        __syncthreads();
        bf16x8 af[4];
#pragma unroll
        for (int t = 0; t < 4; ++t)
            af[t] = *(const bf16x8*)&As[(t * 16 + mrow) * 32 + quad * 8];
        bf16x8 bf = *(const bf16x8*)&Bs[(wc + mrow) * 32 + quad * 8];
#pragma unroll
        for (int rt = 0; rt < 4; ++rt)
            acc[rt] = __builtin_amdgcn_mfma_f32_16x16x32_bf16(af[rt], bf, acc[rt], 0, 0, 0);
    }
    int col = kt * 64 + wc + mrow;
#pragma unroll
    for (int rt = 0; rt < 4; ++rt) {
        int row = it * 64 + rt * 16 + quad * 4;
#pragma unroll
        for (int e = 0; e < 4; ++e)
            S[((size_t)z * T_ + row + e) * T_ + col] = f2bf(acc[rt][e] * 0.125f);
    }
}

// ======================= per-row decay + double softmax, one WAVE per row ==========
// 2 elements/lane: k = c*128 + 2*lane + {0,1}. Wave-uniform break skips inactive
// chunks (R5 block-per-row experiment: no-skip = exactly 2x time -> issue-bound
// at fixed cost/element; this structure is the efficient one).
// Trims vs the 77us version:
//  - softmax#2 max PASS DELETED: gam<0 => eff<=1 => s*eff <= max(mx,0); softmax
//    is shift-invariant, bound mx2=max(mx,0) causes no overflow, underflow only
//    where true softmax also rounds to 0 in bf16.
//  - 1/tot via v_rcp_f32 (1 ulp; tolerance is 0.0625) instead of precise-div
//    expansion (~10 ops each).
#define LOG2E 1.4426950408889634f

// update_dpp: lanes with invalid source get OLDB (identity).
#define DPPF(OLDB, X, CTRL, RM) \
    __uint_as_float((u32)__builtin_amdgcn_update_dpp( \
        (int)(OLDB), __float_as_int(X), CTRL, RM, 0xf, false))

__device__ __forceinline__ float scan_add_f(float x) {   // inclusive 64-lane prefix sum
    x += DPPF(0u, x, 0x111, 0xf);   // row_shr:1
    x += DPPF(0u, x, 0x112, 0xf);   // row_shr:2
    x += DPPF(0u, x, 0x114, 0xf);   // row_shr:4
    x += DPPF(0u, x, 0x118, 0xf);   // row_shr:8
    x += DPPF(0u, x, 0x142, 0xa);   // row_bcast:15 -> rows 1,3
    x += DPPF(0u, x, 0x143, 0xc);   // row_bcast:31 -> rows 2,3
    return x;
}
__device__ __forceinline__ float scan_max_f(float x) {   // inclusive 64-lane prefix max
    x = fmaxf(x, DPPF(0xff800000u, x, 0x111, 0xf));
    x = fmaxf(x, DPPF(0xff800000u, x, 0x112, 0xf));
    x = fmaxf(x, DPPF(0xff800000u, x, 0x114, 0xf));
    x = fmaxf(x, DPPF(0xff800000u, x, 0x118, 0xf));
    x = fmaxf(x, DPPF(0xff800000u, x, 0x142, 0xa));
    x = fmaxf(x, DPPF(0xff800000u, x, 0x143, 0xc));
    return x;
}
__device__ __forceinline__ float lane63(float x) {       // broadcast lane 63 (uniform)
    return __uint_as_float((u32)__builtin_amdgcn_readlane(__float_as_int(x), 63));
}

__global__ void __launch_bounds__(256) decay_rows(
    u16* __restrict__ S, const float* __restrict__ gam_l, int mtype)
{
    int tid = threadIdx.x;
    int wv = tid >> 6, lane = tid & 63;
    int i = blockIdx.x * 4 + wv;
    int z = blockIdx.y;
    int h = z & 7;
    u16* row = S + ((size_t)z * T_ + i) * T_;
    int kmax = (mtype == 0) ? (i - 1) : i;

    if (kmax < 0) {                     // mtype==0, i==0 (zero_pad row); PV reads k<64
        row[lane] = 0;
        return;
    }
    int nc    = (kmax >> 7) + 1;        // active 128-wide chunks (<= 8)
    int nfull = (kmax + 1) >> 7;        // chunks with no masked element
    int wend  = (((i >> 6) + 1) * 64 + 127) >> 7;  // chunks PV reads (zero-fill to here)

    float s0[8], s1[8], p0[8], p1[8];
    int base = lane * 2;

    // ---- load (log2e-scaled), mask boundary chunk only, per-lane max ----
    float mx = -1e30f;
#pragma unroll
    for (int c = 0; c < 8; ++c) {
        if (c >= nc) break;
        int k = c * 128 + base;
        u32 v = *(const u32*)(row + k);
        float a = __uint_as_float(v << 16) * LOG2E;
        float b = __uint_as_float(v & 0xffff0000u) * LOG2E;
        if (c >= nfull) {               // only the boundary chunk needs masking
            a = (k     <= kmax) ? a : -1.5e30f;
            b = (k + 1 <= kmax) ? b : -1.5e30f;
        }
        s0[c] = a; s1[c] = b;
        mx = fmaxf(mx, fmaxf(a, b));
    }
    mx = lane63(scan_max_f(mx));

    // ---- softmax #1 (unnormalized; masked -> exp2 underflow 0) ----
    float t1 = 0.f;
#pragma unroll
    for (int c = 0; c < 8; ++c) {
        if (c >= nc) break;
        float e0 = __builtin_amdgcn_exp2f(s0[c] - mx);
        float e1 = __builtin_amdgcn_exp2f(s1[c] - mx);
        p0[c] = e0; p1[c] = e1;
        t1 += e0 + e1;
    }
    float tot = lane63(scan_add_f(t1));
    float inv1 = __builtin_amdgcn_rcpf(tot);

    // ---- pair-scan cumsum (DPP) + distance effect ----
    float gam = -log1pf(__expf(gam_l[h])) * LOG2E;   // log2e folded into gamma
    float fi = (float)i;
    float kf = (float)base;
    float running = 0.f;
#pragma unroll
    for (int c = 0; c < 8; ++c) {
        if (c >= nc) break;
        float sc = scan_add_f(p0[c] + p1[c]);
        float incl1 = running + sc;
        float incl0 = incl1 - p1[c];
        running += lane63(sc);
        float rem0 = fmaxf((tot - incl0) * inv1, 0.f);
        float rem1 = fmaxf((tot - incl1) * inv1, 0.f);
        float pos0 = fabsf(kf - fi);
        float pos1 = fabsf(kf + 1.f - fi);
        float ef0 = __builtin_amdgcn_fmed3f(
            __builtin_amdgcn_exp2f(sqrtf(rem0 * pos0) * gam), 1e-5f, 1e5f);
        float ef1 = __builtin_amdgcn_fmed3f(
            __builtin_amdgcn_exp2f(sqrtf(rem1 * pos1) * gam), 1e-5f, 1e5f);
        s0[c] *= ef0;                   // masked: -1.5e30*eff <= -1.5e25, still excluded
        s1[c] *= ef1;
        kf += 128.f;
    }

    // ---- softmax #2: shift by BOUND max(mx,0) (eff<=1 => s*eff <= max(mx,0)) ----
    float mx2 = fmaxf(mx, 0.f);
    float t2 = 0.f;
#pragma unroll
    for (int c = 0; c < 8; ++c) {
        if (c >= nc) break;
        float e0 = __builtin_amdgcn_exp2f(s0[c] - mx2);
        float e1 = __builtin_amdgcn_exp2f(s1[c] - mx2);
        p0[c] = e0; p1[c] = e1;
        t2 += e0 + e1;
    }
    float tot2 = lane63(scan_add_f(t2));
    float inv2 = __builtin_amdgcn_rcpf(tot2);

    // ---- write P (v_cvt_pk_bf16_f32), zero-fill tail chunks PV reads ----
#pragma unroll
    for (int c = 0; c < 8; ++c) {
        if (c >= nc) break;
        float lo = p0[c] * inv2, hi = p1[c] * inv2;
        u32 o;
        asm("v_cvt_pk_bf16_f32 %0, %1, %2" : "=v"(o) : "v"(lo), "v"(hi));
        *(u32*)(row + c * 128 + base) = o;
    }
#pragma unroll
    for (int c = 0; c < 8; ++c) {
        if (c < nc) continue;
        if (c >= wend) break;
        *(u32*)(row + c * 128 + base) = 0u;
    }
}

// ======================= PV MFMA: O = P(bf16) x V, causal K-bound =======================
__global__ void __launch_bounds__(256) pv_mfma(
    const u16* __restrict__ P, const u16* __restrict__ Vt,
    u16* __restrict__ O)
{
    int mt = blockIdx.x;
    int z = blockIdx.y;
    int b = z >> 3, h = z & 7;
    __shared__ __align__(16) u16 As[64 * 32];
    __shared__ __align__(16) u16 Bs[64 * 32];
    int tid = threadIdx.x;
    int wid = tid >> 6, lane = tid & 63;
    int quad = lane >> 4, mrow = lane & 15;
    int wc = wid * 16;

    const u16* Ap = P + ((size_t)z * T_ + mt * 64 + (tid >> 2)) * T_ + (tid & 3) * 8;
    const u16* Bp = Vt + ((size_t)z * DK_ + (tid >> 2)) * T_ + (tid & 3) * 8;
    char* lA = (char*)As + wid * 1024;
    char* lB = (char*)Bs + wid * 1024;

    int kend = (mt + 1) * 64;
    f32x4 acc[4] = {};
    for (int k0 = 0; k0 < kend; k0 += 32) {
        __syncthreads();
        gload16(Ap + k0, lA);
        gload16(Bp + k0, lB);
        asm volatile("s_waitcnt vmcnt(0)" ::: "memory");
        __syncthreads();
        bf16x8 af[4];
#pragma unroll
        for (int t = 0; t < 4; ++t)
            af[t] = *(const bf16x8*)&As[(t * 16 + mrow) * 32 + quad * 8];
        bf16x8 bf = *(const bf16x8*)&Bs[(wc + mrow) * 32 + quad * 8];
#pragma unroll
        for (int rt = 0; rt < 4; ++rt)
            acc[rt] = __builtin_amdgcn_mfma_f32_16x16x32_bf16(af[rt], bf, acc[rt], 0, 0, 0);
    }
    int col = h * DK_ + wc + mrow;
#pragma unroll
    for (int rt = 0; rt < 4; ++rt) {
        int row = b * T_ + mt * 64 + rt * 16 + quad * 4;
#pragma unroll
        for (int e = 0; e < 4; ++e)
            O[(size_t)(row + e) * D_ + col] = f2bf(acc[rt][e]);
    }
}

// ======================= prep kernels =======================
__global__ void __launch_bounds__(256) transpose_bf16(
    const float* __restrict__ W, u16* __restrict__ Wt, int K, int N)
{
    __shared__ float tile[32][33];
    size_t base = (size_t)blockIdx.z * K * N;
    W += base; Wt += base;
    int k0 = blockIdx.y * 32, n0 = blockIdx.x * 32;
    int r = threadIdx.x >> 3, c = (threadIdx.x & 7) * 4;
    float4 v = *(const float4*)(W + (size_t)(k0 + r) * N + n0 + c);
    tile[r][c] = v.x; tile[r][c + 1] = v.y; tile[r][c + 2] = v.z; tile[r][c + 3] = v.w;
    __syncthreads();
    ushort4 o;
    o.x = f2bf(tile[c + 0][r]); o.y = f2bf(tile[c + 1][r]);
    o.z = f2bf(tile[c + 2][r]); o.w = f2bf(tile[c + 3][r]);
    *(ushort4*)(Wt + (size_t)(n0 + r) * K + k0 + c) = o;
}

__global__ void w5_gather(const float* __restrict__ cw, u16* __restrict__ W5t)
{
    int idx = blockIdx.x * 256 + threadIdx.x;
    if (idx >= 5 * D_ * D_) return;
    int ks = idx / (D_ * D_);
    int rem = idx - ks * (D_ * D_);
    int o = rem >> 9, i = rem & (D_ - 1);
    W5t[idx] = f2bf(cw[((size_t)o * D_ + i) * 5 + ks]);
}

__global__ void cast_pad(const float* __restrict__ x, const float* __restrict__ y,
                         u16* __restrict__ Xp, u16* __restrict__ Yp)
{
    int idx = blockIdx.x * 256 + threadIdx.x;
    if (idx >= BSZ * TP_ * D_) return;
    int d = idx & (D_ - 1);
    int rowp = idx >> 9;
    int b = rowp / TP_;
    int t = rowp - b * TP_;
    u16 vx = 0, vy = 0;
    if (t >= 4) {
        size_t src = ((size_t)(b * T_ + t - 4) << 9) + d;
        vx = f2bf(x[src]); vy = f2bf(y[src]);
    }
    Xp[idx] = vx; Yp[idx] = vy;
}

// ======================= smooth pointwise + LayerNorm (eps=1e-12) =======================
__global__ void __launch_bounds__(256) smooth_ln(
    const float* __restrict__ x, const float* __restrict__ trend,
    const float* __restrict__ conv_b, const float* __restrict__ sqrt_beta,
    const float* __restrict__ g, const float* __restrict__ bb,
    float* __restrict__ out, u16* __restrict__ outb)
{
    __shared__ float s_red[8];
    int row = blockIdx.x, tid = threadIdx.x;
    int lane = tid & 63, wid = tid >> 6;
    float2 xv = ((const float2*)(x + (size_t)row * D_))[tid];
    float2 tv = ((const float2*)(trend + (size_t)row * D_))[tid];
    float2 cb = ((const float2*)conv_b)[tid];
    float2 sb = ((const float2*)sqrt_beta)[tid];
    float t0 = tv.x + cb.x, t1 = tv.y + cb.y;
    float v0 = t0 + sb.x * sb.x * (xv.x - t0) + xv.x;
    float v1 = t1 + sb.y * sb.y * (xv.y - t1) + xv.y;
    float s = v0 + v1, sq = v0 * v0 + v1 * v1;
    for (int o = 32; o > 0; o >>= 1) { s += __shfl_xor(s, o, 64); sq += __shfl_xor(sq, o, 64); }
    if (lane == 0) { s_red[wid] = s; s_red[4 + wid] = sq; }
    __syncthreads();
    s = s_red[0] + s_red[1] + s_red[2] + s_red[3];
    sq = s_red[4] + s_red[5] + s_red[6] + s_red[7];
    float mean = s * (1.f / D_);
    float var = sq * (1.f / D_) - mean * mean;
    if (var < 0.f) var = 0.f;
    float rstd = rsqrtf(var + 1e-12f);
    float2 gv = ((const float2*)g)[tid];
    float2 bv = ((const float2*)bb)[tid];
    float2 o2;
    o2.x = gv.x * (v0 - mean) * rstd + bv.x;
    o2.y = gv.y * (v1 - mean) * rstd + bv.y;
    ((float2*)(out + (size_t)row * D_))[tid] = o2;
    ushort2 ob; ob.x = f2bf(o2.x); ob.y = f2bf(o2.y);
    ((ushort2*)(outb + (size_t)row * D_))[tid] = ob;
}

// ======================= residual add + LayerNorm (f32 + bf16 out) =======================
__global__ void __launch_bounds__(256) add_ln(
    const float* __restrict__ a, const float* __restrict__ c,
    const float* __restrict__ g, const float* __restrict__ bb,
    float* __restrict__ out, u16* __restrict__ outb, float eps)
{
    __shared__ float s_red[8];
    int row = blockIdx.x, tid = threadIdx.x;
    int lane = tid & 63, wid = tid >> 6;
    float2 av = ((const float2*)(a + (size_t)row * D_))[tid];
    float2 cv = ((const float2*)(c + (size_t)row * D_))[tid];
    float v0 = av.x + cv.x;
    float v1 = av.y + cv.y;
    float s = v0 + v1, sq = v0 * v0 + v1 * v1;
    for (int o = 32; o > 0; o >>= 1) { s += __shfl_xor(s, o, 64); sq += __shfl_xor(sq, o, 64); }
    if (lane == 0) { s_red[wid] = s; s_red[4 + wid] = sq; }
    __syncthreads();
    s = s_red[0] + s_red[1] + s_red[2] + s_red[3];
    sq = s_red[4] + s_red[5] + s_red[6] + s_red[7];
    float mean = s * (1.f / D_);
    float var = sq * (1.f / D_) - mean * mean;
    if (var < 0.f) var = 0.f;
    float rstd = rsqrtf(var + eps);
    float2 gv = ((const float2*)g)[tid];
    float2 bv = ((const float2*)bb)[tid];
    float2 o2;
    o2.x = gv.x * (v0 - mean) * rstd + bv.x;
    o2.y = gv.y * (v1 - mean) * rstd + bv.y;
    ((float2*)(out + (size_t)row * D_))[tid] = o2;
    ushort2 ob; ob.x = f2bf(o2.x); ob.y = f2bf(o2.y);
    ((ushort2*)(outb + (size_t)row * D_))[tid] = ob;
}

// ======================= launch =======================
extern "C" void kernel_launch(void* const* d_in, const int* in_sizes, int n_in,
                              void* d_out, int out_size, void* d_ws, size_t ws_size,
                              hipStream_t stream)
{
    const float* q_embed   = (const float*)d_in[0];
    const float* qa_embed  = (const float*)d_in[1];
    const float* conv_w    = (const float*)d_in[3];
    const float* conv_b    = (const float*)d_in[4];
    const float* sqrt_beta = (const float*)d_in[5];
    const float* sm_g      = (const float*)d_in[6];
    const float* sm_b      = (const float*)d_in[7];
    const float* k_w       = (const float*)d_in[8];
    const float* k_b       = (const float*)d_in[9];
    const float* v_w       = (const float*)d_in[10];
    const float* v_b       = (const float*)d_in[11];
    const float* out_w     = (const float*)d_in[12];
    const float* out_b     = (const float*)d_in[13];
    const float* gammas    = (const float*)d_in[14];
    const float* ln1_g     = (const float*)d_in[15];
    const float* ln1_b     = (const float*)d_in[16];
    const float* ff1_w     = (const float*)d_in[17];
    const float* ff1_b     = (const float*)d_in[18];
    const float* ff2_w     = (const float*)d_in[19];
    const float* ff2_b     = (const float*)d_in[20];
    const float* ln2_g     = (const float*)d_in[21];
    const float* ln2_b     = (const float*)d_in[22];

    const size_t NT = (size_t)M_ * D_;
    float* X = (float*)d_out;
    char* w = (char*)d_ws;
    float* Y  = (float*)w; w += NT * 4;          // 16 MB
    float* Fb = (float*)w; w += NT * 4;          // 16 MB
    u16* Sb = (u16*)w;                           // scores/P bf16: 128 MB
    u16* Hb = Sb;                                // aliases: ffn hidden bf16 (32 MB)
    u16* Xpad = Sb;                              // aliases: prep buffers
    u16* Ypad = Xpad + (size_t)BSZ * TP_ * D_;
    u16* W5t  = Ypad + (size_t)BSZ * TP_ * D_;
    w += (size_t)BSZ * H_ * T_ * T_ * 2;
    u16* Xb  = (u16*)w; w += NT * 2;
    u16* Yb  = (u16*)w; w += NT * 2;
    u16* Cb  = (u16*)w; w += NT * 2;
    u16* Qh  = (u16*)w; w += NT * 2;
    u16* Vt  = (u16*)w; w += NT * 2;
    u16* KWt = (u16*)w; w += (size_t)6 * D_ * D_ * 2;
    u16* VWt = (u16*)w; w += (size_t)6 * D_ * D_ * 2;
    u16* OWt = (u16*)w; w += (size_t)6 * D_ * D_ * 2;
    u16* F1t = (u16*)w; w += (size_t)6 * D_ * FF_ * 2;
    u16* F2t = (u16*)w; w += (size_t)6 * FF_ * D_ * 2;

    dim3 blk(256);

    // ---- prep ----
    cast_pad<<<(BSZ * TP_ * D_ + 255) / 256, blk, 0, stream>>>(q_embed, qa_embed, Xpad, Ypad);
    w5_gather<<<(5 * D_ * D_ + 255) / 256, blk, 0, stream>>>(conv_w, W5t);
    transpose_bf16<<<dim3(D_ / 32, D_ / 32, 6), blk, 0, stream>>>(k_w, KWt, D_, D_);
    transpose_bf16<<<dim3(D_ / 32, D_ / 32, 6), blk, 0, stream>>>(v_w, VWt, D_, D_);
    transpose_bf16<<<dim3(D_ / 32, D_ / 32, 6), blk, 0, stream>>>(out_w, OWt, D_, D_);
    transpose_bf16<<<dim3(FF_ / 32, D_ / 32, 6), blk, 0, stream>>>(ff1_w, F1t, D_, FF_);
    transpose_bf16<<<dim3(D_ / 32, FF_ / 32, 6), blk, 0, stream>>>(ff2_w, F2t, FF_, D_);

    // ---- smooth(x), smooth(y) ----  (64-tile conv: 1024 blocks = 4/CU)
    conv64_mfma<<<dim3(8, 128), blk, 0, stream>>>(Xpad, W5t, Fb);
    smooth_ln<<<M_, blk, 0, stream>>>(q_embed, Fb, conv_b, sqrt_beta, sm_g, sm_b, X, Xb);
    conv64_mfma<<<dim3(8, 128), blk, 0, stream>>>(Ypad, W5t, Fb);
    smooth_ln<<<M_, blk, 0, stream>>>(qa_embed, Fb, conv_b, sqrt_beta, sm_g, sm_b, Y, Yb);

    auto layer = [&](int l, int mtype, float* io, u16* iob, const u16* vinb, bool ffn) {
        gemm64_mfma<<<dim3(8, 128), blk, 0, stream>>>(iob, KWt + (size_t)l * D_ * D_,
                                                      k_b + (size_t)l * D_, Qh, D_, D_, 2);
        gemm64_mfma<<<dim3(8, 128), blk, 0, stream>>>(vinb, VWt + (size_t)l * D_ * D_,
                                                      v_b + (size_t)l * D_, Vt, D_, D_, 3);
        qk_mfma<<<dim3(16, 16, 64), blk, 0, stream>>>(Qh, Sb);
        decay_rows<<<dim3(T_ / 4, 64), blk, 0, stream>>>(Sb, gammas + l * H_, mtype);
        pv_mfma<<<dim3(16, 64), blk, 0, stream>>>(Sb, Vt, Cb);
        gemm64_mfma<<<dim3(8, 128), blk, 0, stream>>>(Cb, OWt + (size_t)l * D_ * D_,
                                                      out_b + (size_t)l * D_, Fb, D_, D_, 0);
        add_ln<<<M_, blk, 0, stream>>>(io, Fb, ln1_g + l * D_, ln1_b + l * D_, io, iob, 1e-5f);
        if (ffn) {
            gemm_mfma<<<dim3(16, 64), blk, 0, stream>>>(iob, F1t + (size_t)l * D_ * FF_,
                                                        ff1_b + (size_t)l * FF_, Hb, FF_, D_, 1);
            gemm64_mfma<<<dim3(8, 128), blk, 0, stream>>>(Hb, F2t + (size_t)l * FF_ * D_,
                                                          ff2_b + (size_t)l * D_, Fb, D_, FF_, 0);
            add_ln<<<M_, blk, 0, stream>>>(io, Fb, ln2_g + l * D_, ln2_b + l * D_, io, iob, 1e-5f);
        }
    };

    layer(0, 1, Y, Yb, Yb, true);
    layer(1, 1, Y, Yb, Yb, true);
    layer(2, 1, X, Xb, Xb, false);
    layer(3, 0, X, Xb, Yb, true);
    layer(4, 1, X, Xb, Xb, false);
    layer(5, 0, X, Xb, Yb, true);
}

// Round 7
// 1755.441 us; speedup vs baseline: 1.2823x; 1.0281x over previous
//
#include <hip/hip_runtime.h>
#include <math.h>

#define T_  1024
#define D_  512
#define H_  8
#define DK_ 64
#define FF_ 2048
#define BSZ 8
#define M_  (BSZ * T_)   // 8192 rows
#define TP_ (T_ + 4)     // padded rows per batch for causal conv

typedef unsigned short u16;
typedef unsigned int u32;
typedef __attribute__((ext_vector_type(8))) __bf16 bf16x8;
typedef __attribute__((ext_vector_type(4))) float f32x4;

__device__ __forceinline__ u16 f2bf(float f) {            // RNE f32 -> bf16 bits
    unsigned int u = __float_as_uint(f);
    u += 0x7fffu + ((u >> 16) & 1u);
    return (u16)(u >> 16);
}
__device__ __forceinline__ float bf2f(u16 b) {
    return __uint_as_float((unsigned int)b << 16);
}

__device__ __forceinline__ void gload16(const void* g, void* l) {
    // async global->LDS, 16B/lane; LDS dest = wave-uniform base + lane*16
    __builtin_amdgcn_global_load_lds(
        (const __attribute__((address_space(1))) void*)g,
        (__attribute__((address_space(3))) void*)l, 16, 0, 0);
}

// ======================= bf16 MFMA GEMM (m97 structure) =======================
// C[M][N] = A[M][K](bf16) * Bt[N][K]^T(bf16) + bias. 128x128 tile, 4 waves.
// Used for FFN1 (M=8192, N=2048) where the grid is already 1024 blocks.
__global__ void __launch_bounds__(256) gemm_mfma(
    const u16* __restrict__ A, const u16* __restrict__ Bt,
    const float* __restrict__ bias, void* __restrict__ Cout,
    int N, int K, int mode)
{
    __shared__ __align__(16) u16 As[128 * 32];
    __shared__ __align__(16) u16 Bs[128 * 32];
    int tid = threadIdx.x;
    int wid = tid >> 6, lane = tid & 63;
    int quad = lane >> 4, mrow = lane & 15;
    int m0 = blockIdx.y * 128, n0 = blockIdx.x * 128;
    int wr = (wid >> 1) * 64, wc = (wid & 1) * 64;

    const u16* Ap = A + (size_t)(m0 + (tid >> 2)) * K + (tid & 3) * 8;
    const u16* Bp = Bt + (size_t)(n0 + (tid >> 2)) * K + (tid & 3) * 8;
    char* lA = (char*)As + wid * 1024;
    char* lB = (char*)Bs + wid * 1024;

    f32x4 acc[4][4] = {};
    for (int k0 = 0; k0 < K; k0 += 32) {
        __syncthreads();
        gload16(Ap + k0, lA);
        gload16(Ap + (size_t)64 * K + k0, lA + 4096);
        gload16(Bp + k0, lB);
        gload16(Bp + (size_t)64 * K + k0, lB + 4096);
        asm volatile("s_waitcnt vmcnt(0)" ::: "memory");
        __syncthreads();
        bf16x8 af[4], bf[4];
#pragma unroll
        for (int t = 0; t < 4; ++t) {
            af[t] = *(const bf16x8*)&As[(wr + t * 16 + mrow) * 32 + quad * 8];
            bf[t] = *(const bf16x8*)&Bs[(wc + t * 16 + mrow) * 32 + quad * 8];
        }
#pragma unroll
        for (int rt = 0; rt < 4; ++rt)
#pragma unroll
            for (int ct = 0; ct < 4; ++ct)
                acc[rt][ct] = __builtin_amdgcn_mfma_f32_16x16x32_bf16(
                    af[rt], bf[ct], acc[rt][ct], 0, 0, 0);
    }

#pragma unroll
    for (int ct = 0; ct < 4; ++ct) {
        int col = n0 + wc + ct * 16 + mrow;
        float bv = bias ? bias[col] : 0.f;
#pragma unroll
        for (int rt = 0; rt < 4; ++rt) {
            int rowb = m0 + wr + rt * 16 + quad * 4;
            if (mode == 0) {
                float* C = (float*)Cout;
#pragma unroll
                for (int e = 0; e < 4; ++e)
                    C[(size_t)(rowb + e) * N + col] = acc[rt][ct][e] + bv;
            } else if (mode == 1) {
                u16* C = (u16*)Cout;
#pragma unroll
                for (int e = 0; e < 4; ++e)
                    C[(size_t)(rowb + e) * N + col] = f2bf(fmaxf(acc[rt][ct][e] + bv, 0.f));
            } else {
                u16* C = (u16*)Cout;
#pragma unroll
                for (int e = 0; e < 4; ++e)
                    C[(size_t)(rowb + e) * N + col] = f2bf(acc[rt][ct][e] + bv);
            }
        }
    }
}

// ======================= bf16 MFMA GEMM, 64x64 tile (high-occupancy) =======================
// Grid (N/64, M/64) -> 1024+ blocks = 4+ blocks/CU.
// modes: 0 f32; 1 bf16 relu; 2 bf16; 3 per-head-transposed bf16 Vt.
__global__ void __launch_bounds__(256) gemm64_mfma(
    const u16* __restrict__ A, const u16* __restrict__ Bt,
    const float* __restrict__ bias, void* __restrict__ Cout,
    int N, int K, int mode)
{
    __shared__ __align__(16) u16 As[64 * 32];
    __shared__ __align__(16) u16 Bs[64 * 32];
    int tid = threadIdx.x;
    int wid = tid >> 6, lane = tid & 63;
    int quad = lane >> 4, mrow = lane & 15;
    int m0 = blockIdx.y * 64, n0 = blockIdx.x * 64;
    int wc = wid * 16;

    const u16* Ap = A + (size_t)(m0 + (tid >> 2)) * K + (tid & 3) * 8;
    const u16* Bp = Bt + (size_t)(n0 + (tid >> 2)) * K + (tid & 3) * 8;
    char* lA = (char*)As + wid * 1024;
    char* lB = (char*)Bs + wid * 1024;

    f32x4 acc[4] = {};
    for (int k0 = 0; k0 < K; k0 += 32) {
        __syncthreads();
        gload16(Ap + k0, lA);
        gload16(Bp + k0, lB);
        asm volatile("s_waitcnt vmcnt(0)" ::: "memory");
        __syncthreads();
        bf16x8 af[4];
#pragma unroll
        for (int t = 0; t < 4; ++t)
            af[t] = *(const bf16x8*)&As[(t * 16 + mrow) * 32 + quad * 8];
        bf16x8 bf = *(const bf16x8*)&Bs[(wc + mrow) * 32 + quad * 8];
#pragma unroll
        for (int rt = 0; rt < 4; ++rt)
            acc[rt] = __builtin_amdgcn_mfma_f32_16x16x32_bf16(af[rt], bf, acc[rt], 0, 0, 0);
    }

    int col = n0 + wc + mrow;
    float bv = bias ? bias[col] : 0.f;
#pragma unroll
    for (int rt = 0; rt < 4; ++rt) {
        int rowb = m0 + rt * 16 + quad * 4;
        if (mode == 0) {
            float* C = (float*)Cout;
#pragma unroll
            for (int e = 0; e < 4; ++e)
                C[(size_t)(rowb + e) * N + col] = acc[rt][e] + bv;
        } else if (mode == 1) {
            u16* C = (u16*)Cout;
#pragma unroll
            for (int e = 0; e < 4; ++e)
                C[(size_t)(rowb + e) * N + col] = f2bf(fmaxf(acc[rt][e] + bv, 0.f));
        } else if (mode == 2) {
            u16* C = (u16*)Cout;
#pragma unroll
            for (int e = 0; e < 4; ++e)
                C[(size_t)(rowb + e) * N + col] = f2bf(acc[rt][e] + bv);
        } else {
            u16* C = (u16*)Cout;
            int h = col >> 6, dl = col & 63;
#pragma unroll
            for (int e = 0; e < 4; ++e) {
                int row = rowb + e;
                int b = row >> 10, t = row & (T_ - 1);
                C[(((size_t)(b * H_ + h) * DK_ + dl) << 10) + t] =
                    f2bf(acc[rt][e] + bv);
            }
        }
    }
}

// ======================= causal conv1d: 5 shifted passes, 64x64 tile =======================
__global__ void __launch_bounds__(256) conv64_mfma(
    const u16* __restrict__ Xp, const u16* __restrict__ W5t, float* __restrict__ C)
{
    __shared__ __align__(16) u16 As[64 * 32];
    __shared__ __align__(16) u16 Bs[64 * 32];
    int tid = threadIdx.x;
    int wid = tid >> 6, lane = tid & 63;
    int quad = lane >> 4, mrow = lane & 15;
    int m0 = blockIdx.y * 64, n0 = blockIdx.x * 64;
    int wc = wid * 16;
    int b = m0 >> 10, tloc = m0 & (T_ - 1);

    const u16* Ap0 = Xp + (size_t)(b * TP_ + tloc + (tid >> 2)) * D_ + (tid & 3) * 8;
    const u16* Bp0 = W5t + (size_t)(n0 + (tid >> 2)) * D_ + (tid & 3) * 8;
    char* lA = (char*)As + wid * 1024;
    char* lB = (char*)Bs + wid * 1024;

    f32x4 acc[4] = {};
    for (int ks = 0; ks < 5; ++ks) {
        const u16* Ap = Ap0 + ks * D_;
        const u16* Bp = Bp0 + (size_t)ks * D_ * D_;
        for (int k0 = 0; k0 < D_; k0 += 32) {
            __syncthreads();
            gload16(Ap + k0, lA);
            gload16(Bp + k0, lB);
            asm volatile("s_waitcnt vmcnt(0)" ::: "memory");
            __syncthreads();
            bf16x8 af[4];
#pragma unroll
            for (int t = 0; t < 4; ++t)
                af[t] = *(const bf16x8*)&As[(t * 16 + mrow) * 32 + quad * 8];
            bf16x8 bf = *(const bf16x8*)&Bs[(wc + mrow) * 32 + quad * 8];
#pragma unroll
            for (int rt = 0; rt < 4; ++rt)
                acc[rt] = __builtin_amdgcn_mfma_f32_16x16x32_bf16(af[rt], bf, acc[rt], 0, 0, 0);
        }
    }
    int col = n0 + wc + mrow;
#pragma unroll
    for (int rt = 0; rt < 4; ++rt) {
        int row = m0 + rt * 16 + quad * 4;
#pragma unroll
        for (int e = 0; e < 4; ++e)
            C[(size_t)(row + e) * D_ + col] = acc[rt][e];
    }
}

// ======================= QK^T MFMA: S[z][i][k] bf16, causal tiles =======================
__global__ void __launch_bounds__(256) qk_mfma(
    const u16* __restrict__ Qh, u16* __restrict__ S)
{
    int kt = blockIdx.x, it = blockIdx.y;
    if (kt > it) return;
    int z = blockIdx.z;
    int b = z >> 3, h = z & 7;
    __shared__ __align__(16) u16 As[64 * 32];
    __shared__ __align__(16) u16 Bs[64 * 32];
    int tid = threadIdx.x;
    int wid = tid >> 6, lane = tid & 63;
    int quad = lane >> 4, mrow = lane & 15;
    int wc = wid * 16;

    const u16* Ap = Qh + (size_t)(b * T_ + it * 64 + (tid >> 2)) * D_ + h * DK_ + (tid & 3) * 8;
    const u16* Bp = Qh + (size_t)(b * T_ + kt * 64 + (tid >> 2)) * D_ + h * DK_ + (tid & 3) * 8;
    char* lA = (char*)As + wid * 1024;
    char* lB = (char*)Bs + wid * 1024;

    f32x4 acc[4] = {};
#pragma unroll
    for (int k0 = 0; k0 < DK_; k0 += 32) {
        __syncthreads();
        gload16(Ap + k0, lA);
        gload16(Bp + k0, lB);
        asm volatile("s_waitcnt vmcnt(0)" ::: "memory");
        __syncthreads();
        bf16x8 af[4];
#pragma unroll
        for (int t = 0; t < 4; ++t)
            af[t] = *(const bf16x8*)&As[(t * 16 + mrow) * 32 + quad * 8];
        bf16x8 bf = *(const bf16x8*)&Bs[(wc + mrow) * 32 + quad * 8];
#pragma unroll
        for (int rt = 0; rt < 4; ++rt)
            acc[rt] = __builtin_amdgcn_mfma_f32_16x16x32_bf16(af[rt], bf, acc[rt], 0, 0, 0);
    }
    int col = kt * 64 + wc + mrow;
#pragma unroll
    for (int rt = 0; rt < 4; ++rt) {
        int row = it * 64 + rt * 16 + quad * 4;
#pragma unroll
        for (int e = 0; e < 4; ++e)
            S[((size_t)z * T_ + row + e) * T_ + col] = f2bf(acc[rt][e] * 0.125f);
    }
}

// ======================= per-row decay + double softmax, one WAVE per row ==========
// 2 elements/lane: k = c*128 + 2*lane + {0,1}. R6 had runtime `if (c>=nc) break`
// in 4 separate passes -> compiler keeps per-chunk branch/exec scaffolding and
// emits ~4x the useful ops (measured 1380 slots/wave vs ~350 modeled). Here the
// wave-uniform nc dispatches ONCE into template<NC> fully-unrolled bodies:
// no per-chunk branches, masking only on chunk NC-1 (earlier chunks provably
// full), and softmax#2's exp2 fused into the effect pass (its shift
// mx2=max(mx,0) is known before the scan -- R6's bound, eff<=1).
#define LOG2E 1.4426950408889634f

// update_dpp: lanes with invalid source get OLDB (identity).
#define DPPF(OLDB, X, CTRL, RM) \
    __uint_as_float((u32)__builtin_amdgcn_update_dpp( \
        (int)(OLDB), __float_as_int(X), CTRL, RM, 0xf, false))

__device__ __forceinline__ float scan_add_f(float x) {   // inclusive 64-lane prefix sum
    x += DPPF(0u, x, 0x111, 0xf);   // row_shr:1
    x += DPPF(0u, x, 0x112, 0xf);   // row_shr:2
    x += DPPF(0u, x, 0x114, 0xf);   // row_shr:4
    x += DPPF(0u, x, 0x118, 0xf);   // row_shr:8
    x += DPPF(0u, x, 0x142, 0xa);   // row_bcast:15 -> rows 1,3
    x += DPPF(0u, x, 0x143, 0xc);   // row_bcast:31 -> rows 2,3
    return x;
}
__device__ __forceinline__ float scan_max_f(float x) {   // inclusive 64-lane prefix max
    x = fmaxf(x, DPPF(0xff800000u, x, 0x111, 0xf));
    x = fmaxf(x, DPPF(0xff800000u, x, 0x112, 0xf));
    x = fmaxf(x, DPPF(0xff800000u, x, 0x114, 0xf));
    x = fmaxf(x, DPPF(0xff800000u, x, 0x118, 0xf));
    x = fmaxf(x, DPPF(0xff800000u, x, 0x142, 0xa));
    x = fmaxf(x, DPPF(0xff800000u, x, 0x143, 0xc));
    return x;
}
__device__ __forceinline__ float lane63(float x) {       // broadcast lane 63 (uniform)
    return __uint_as_float((u32)__builtin_amdgcn_readlane(__float_as_int(x), 63));
}

template<int NC>
__device__ __forceinline__ void decay_body(
    u16* __restrict__ row, int kmax, float gam, float fi, int lane, int wend)
{
    int base = lane * 2;
    float s0[NC], s1[NC], p0[NC], p1[NC];

    // ---- pass 1: load (log2e-scaled), mask boundary chunk, wave max ----
    float mx = -1e30f;
#pragma unroll
    for (int c = 0; c < NC; ++c) {
        int k = c * 128 + base;
        u32 v = *(const u32*)(row + k);
        float a = __uint_as_float(v << 16) * LOG2E;
        float b = __uint_as_float(v & 0xffff0000u) * LOG2E;
        if (c == NC - 1) {              // chunks < NC-1 are provably all <= kmax
            a = (k     <= kmax) ? a : -1.5e30f;
            b = (k + 1 <= kmax) ? b : -1.5e30f;
        }
        s0[c] = a; s1[c] = b;
        mx = fmaxf(mx, fmaxf(a, b));
    }
    mx = lane63(scan_max_f(mx));

    // ---- pass 2: softmax#1 exps (unnormalized; masked -> underflow 0) ----
    float t1 = 0.f;
#pragma unroll
    for (int c = 0; c < NC; ++c) {
        float e0 = __builtin_amdgcn_exp2f(s0[c] - mx);
        float e1 = __builtin_amdgcn_exp2f(s1[c] - mx);
        p0[c] = e0; p1[c] = e1;
        t1 += e0 + e1;
    }
    float tot = lane63(scan_add_f(t1));
    float inv1 = __builtin_amdgcn_rcpf(tot);
    float mx2 = fmaxf(mx, 0.f);         // bound: eff<=1 => s*eff <= max(mx,0)

    // ---- pass 3 (fused): cumsum scan + distance effect + softmax#2 exp ----
    float t2 = 0.f;
    float running = 0.f;
    float kf = (float)base;
#pragma unroll
    for (int c = 0; c < NC; ++c) {
        float sc = scan_add_f(p0[c] + p1[c]);
        float incl1 = running + sc;
        float incl0 = incl1 - p1[c];
        running += lane63(sc);
        float rem0 = fmaxf((tot - incl0) * inv1, 0.f);
        float rem1 = fmaxf((tot - incl1) * inv1, 0.f);
        float pos0 = fabsf(kf - fi);
        float pos1 = fabsf(kf + 1.f - fi);
        float ef0 = __builtin_amdgcn_fmed3f(
            __builtin_amdgcn_exp2f(sqrtf(rem0 * pos0) * gam), 1e-5f, 1e5f);
        float ef1 = __builtin_amdgcn_fmed3f(
            __builtin_amdgcn_exp2f(sqrtf(rem1 * pos1) * gam), 1e-5f, 1e5f);
        // masked: s = -1.5e30, s*ef <= -1.5e25 -> exp2 underflows to 0
        float e0 = __builtin_amdgcn_exp2f(s0[c] * ef0 - mx2);
        float e1 = __builtin_amdgcn_exp2f(s1[c] * ef1 - mx2);
        p0[c] = e0; p1[c] = e1;
        t2 += e0 + e1;
        kf += 128.f;
    }
    float inv2 = __builtin_amdgcn_rcpf(lane63(scan_add_f(t2)));

    // ---- pass 4: write P (v_cvt_pk_bf16_f32), zero-fill tail PV reads ----
#pragma unroll
    for (int c = 0; c < NC; ++c) {
        float lo = p0[c] * inv2, hi = p1[c] * inv2;
        u32 o;
        asm("v_cvt_pk_bf16_f32 %0, %1, %2" : "=v"(o) : "v"(lo), "v"(hi));
        *(u32*)(row + c * 128 + base) = o;
    }
    for (int c = NC; c < wend; ++c)
        *(u32*)(row + c * 128 + base) = 0u;
}

__global__ void __launch_bounds__(256) decay_rows(
    u16* __restrict__ S, const float* __restrict__ gam_l, int mtype)
{
    int tid = threadIdx.x;
    int wv = tid >> 6, lane = tid & 63;
    int i = blockIdx.x * 4 + wv;
    int z = blockIdx.y;
    int h = z & 7;
    u16* row = S + ((size_t)z * T_ + i) * T_;
    int kmax = (mtype == 0) ? (i - 1) : i;

    if (kmax < 0) {                     // mtype==0, i==0 (zero_pad row); PV reads k<64
        row[lane] = 0;
        return;
    }
    int nc   = (kmax >> 7) + 1;         // active 128-wide chunks (1..8), wave-uniform
    int wend = (((i >> 6) + 1) * 64 + 127) >> 7;  // chunks PV reads (zero-fill to here)
    float gam = -log1pf(__expf(gam_l[h])) * LOG2E;
    float fi = (float)i;

    switch (nc) {
        case 1: decay_body<1>(row, kmax, gam, fi, lane, wend); break;
        case 2: decay_body<2>(row, kmax, gam, fi, lane, wend); break;
        case 3: decay_body<3>(row, kmax, gam, fi, lane, wend); break;
        case 4: decay_body<4>(row, kmax, gam, fi, lane, wend); break;
        case 5: decay_body<5>(row, kmax, gam, fi, lane, wend); break;
        case 6: decay_body<6>(row, kmax, gam, fi, lane, wend); break;
        case 7: decay_body<7>(row, kmax, gam, fi, lane, wend); break;
        default: decay_body<8>(row, kmax, gam, fi, lane, wend); break;
    }
}

// ======================= PV MFMA: O = P(bf16) x V, causal K-bound =======================
__global__ void __launch_bounds__(256) pv_mfma(
    const u16* __restrict__ P, const u16* __restrict__ Vt,
    u16* __restrict__ O)
{
    int mt = blockIdx.x;
    int z = blockIdx.y;
    int b = z >> 3, h = z & 7;
    __shared__ __align__(16) u16 As[64 * 32];
    __shared__ __align__(16) u16 Bs[64 * 32];
    int tid = threadIdx.x;
    int wid = tid >> 6, lane = tid & 63;
    int quad = lane >> 4, mrow = lane & 15;
    int wc = wid * 16;

    const u16* Ap = P + ((size_t)z * T_ + mt * 64 + (tid >> 2)) * T_ + (tid & 3) * 8;
    const u16* Bp = Vt + ((size_t)z * DK_ + (tid >> 2)) * T_ + (tid & 3) * 8;
    char* lA = (char*)As + wid * 1024;
    char* lB = (char*)Bs + wid * 1024;

    int kend = (mt + 1) * 64;
    f32x4 acc[4] = {};
    for (int k0 = 0; k0 < kend; k0 += 32) {
        __syncthreads();
        gload16(Ap + k0, lA);
        gload16(Bp + k0, lB);
        asm volatile("s_waitcnt vmcnt(0)" ::: "memory");
        __syncthreads();
        bf16x8 af[4];
#pragma unroll
        for (int t = 0; t < 4; ++t)
            af[t] = *(const bf16x8*)&As[(t * 16 + mrow) * 32 + quad * 8];
        bf16x8 bf = *(const bf16x8*)&Bs[(wc + mrow) * 32 + quad * 8];
#pragma unroll
        for (int rt = 0; rt < 4; ++rt)
            acc[rt] = __builtin_amdgcn_mfma_f32_16x16x32_bf16(af[rt], bf, acc[rt], 0, 0, 0);
    }
    int col = h * DK_ + wc + mrow;
#pragma unroll
    for (int rt = 0; rt < 4; ++rt) {
        int row = b * T_ + mt * 64 + rt * 16 + quad * 4;
#pragma unroll
        for (int e = 0; e < 4; ++e)
            O[(size_t)(row + e) * D_ + col] = f2bf(acc[rt][e]);
    }
}

// ======================= prep kernels =======================
__global__ void __launch_bounds__(256) transpose_bf16(
    const float* __restrict__ W, u16* __restrict__ Wt, int K, int N)
{
    __shared__ float tile[32][33];
    size_t base = (size_t)blockIdx.z * K * N;
    W += base; Wt += base;
    int k0 = blockIdx.y * 32, n0 = blockIdx.x * 32;
    int r = threadIdx.x >> 3, c = (threadIdx.x & 7) * 4;
    float4 v = *(const float4*)(W + (size_t)(k0 + r) * N + n0 + c);
    tile[r][c] = v.x; tile[r][c + 1] = v.y; tile[r][c + 2] = v.z; tile[r][c + 3] = v.w;
    __syncthreads();
    ushort4 o;
    o.x = f2bf(tile[c + 0][r]); o.y = f2bf(tile[c + 1][r]);
    o.z = f2bf(tile[c + 2][r]); o.w = f2bf(tile[c + 3][r]);
    *(ushort4*)(Wt + (size_t)(n0 + r) * K + k0 + c) = o;
}

__global__ void w5_gather(const float* __restrict__ cw, u16* __restrict__ W5t)
{
    int idx = blockIdx.x * 256 + threadIdx.x;
    if (idx >= 5 * D_ * D_) return;
    int ks = idx / (D_ * D_);
    int rem = idx - ks * (D_ * D_);
    int o = rem >> 9, i = rem & (D_ - 1);
    W5t[idx] = f2bf(cw[((size_t)o * D_ + i) * 5 + ks]);
}

__global__ void cast_pad(const float* __restrict__ x, const float* __restrict__ y,
                         u16* __restrict__ Xp, u16* __restrict__ Yp)
{
    int idx = blockIdx.x * 256 + threadIdx.x;
    if (idx >= BSZ * TP_ * D_) return;
    int d = idx & (D_ - 1);
    int rowp = idx >> 9;
    int b = rowp / TP_;
    int t = rowp - b * TP_;
    u16 vx = 0, vy = 0;
    if (t >= 4) {
        size_t src = ((size_t)(b * T_ + t - 4) << 9) + d;
        vx = f2bf(x[src]); vy = f2bf(y[src]);
    }
    Xp[idx] = vx; Yp[idx] = vy;
}

// ======================= smooth pointwise + LayerNorm (eps=1e-12) =======================
__global__ void __launch_bounds__(256) smooth_ln(
    const float* __restrict__ x, const float* __restrict__ trend,
    const float* __restrict__ conv_b, const float* __restrict__ sqrt_beta,
    const float* __restrict__ g, const float* __restrict__ bb,
    float* __restrict__ out, u16* __restrict__ outb)
{
    __shared__ float s_red[8];
    int row = blockIdx.x, tid = threadIdx.x;
    int lane = tid & 63, wid = tid >> 6;
    float2 xv = ((const float2*)(x + (size_t)row * D_))[tid];
    float2 tv = ((const float2*)(trend + (size_t)row * D_))[tid];
    float2 cb = ((const float2*)conv_b)[tid];
    float2 sb = ((const float2*)sqrt_beta)[tid];
    float t0 = tv.x + cb.x, t1 = tv.y + cb.y;
    float v0 = t0 + sb.x * sb.x * (xv.x - t0) + xv.x;
    float v1 = t1 + sb.y * sb.y * (xv.y - t1) + xv.y;
    float s = v0 + v1, sq = v0 * v0 + v1 * v1;
    for (int o = 32; o > 0; o >>= 1) { s += __shfl_xor(s, o, 64); sq += __shfl_xor(sq, o, 64); }
    if (lane == 0) { s_red[wid] = s; s_red[4 + wid] = sq; }
    __syncthreads();
    s = s_red[0] + s_red[1] + s_red[2] + s_red[3];
    sq = s_red[4] + s_red[5] + s_red[6] + s_red[7];
    float mean = s * (1.f / D_);
    float var = sq * (1.f / D_) - mean * mean;
    if (var < 0.f) var = 0.f;
    float rstd = rsqrtf(var + 1e-12f);
    float2 gv = ((const float2*)g)[tid];
    float2 bv = ((const float2*)bb)[tid];
    float2 o2;
    o2.x = gv.x * (v0 - mean) * rstd + bv.x;
    o2.y = gv.y * (v1 - mean) * rstd + bv.y;
    ((float2*)(out + (size_t)row * D_))[tid] = o2;
    ushort2 ob; ob.x = f2bf(o2.x); ob.y = f2bf(o2.y);
    ((ushort2*)(outb + (size_t)row * D_))[tid] = ob;
}

// ======================= residual add + LayerNorm (f32 + bf16 out) =======================
__global__ void __launch_bounds__(256) add_ln(
    const float* __restrict__ a, const float* __restrict__ c,
    const float* __restrict__ g, const float* __restrict__ bb,
    float* __restrict__ out, u16* __restrict__ outb, float eps)
{
    __shared__ float s_red[8];
    int row = blockIdx.x, tid = threadIdx.x;
    int lane = tid & 63, wid = tid >> 6;
    float2 av = ((const float2*)(a + (size_t)row * D_))[tid];
    float2 cv = ((const float2*)(c + (size_t)row * D_))[tid];
    float v0 = av.x + cv.x;
    float v1 = av.y + cv.y;
    float s = v0 + v1, sq = v0 * v0 + v1 * v1;
    for (int o = 32; o > 0; o >>= 1) { s += __shfl_xor(s, o, 64); sq += __shfl_xor(sq, o, 64); }
    if (lane == 0) { s_red[wid] = s; s_red[4 + wid] = sq; }
    __syncthreads();
    s = s_red[0] + s_red[1] + s_red[2] + s_red[3];
    sq = s_red[4] + s_red[5] + s_red[6] + s_red[7];
    float mean = s * (1.f / D_);
    float var = sq * (1.f / D_) - mean * mean;
    if (var < 0.f) var = 0.f;
    float rstd = rsqrtf(var + eps);
    float2 gv = ((const float2*)g)[tid];
    float2 bv = ((const float2*)bb)[tid];
    float2 o2;
    o2.x = gv.x * (v0 - mean) * rstd + bv.x;
    o2.y = gv.y * (v1 - mean) * rstd + bv.y;
    ((float2*)(out + (size_t)row * D_))[tid] = o2;
    ushort2 ob; ob.x = f2bf(o2.x); ob.y = f2bf(o2.y);
    ((ushort2*)(outb + (size_t)row * D_))[tid] = ob;
}

// ======================= launch =======================
extern "C" void kernel_launch(void* const* d_in, const int* in_sizes, int n_in,
                              void* d_out, int out_size, void* d_ws, size_t ws_size,
                              hipStream_t stream)
{
    const float* q_embed   = (const float*)d_in[0];
    const float* qa_embed  = (const float*)d_in[1];
    const float* conv_w    = (const float*)d_in[3];
    const float* conv_b    = (const float*)d_in[4];
    const float* sqrt_beta = (const float*)d_in[5];
    const float* sm_g      = (const float*)d_in[6];
    const float* sm_b      = (const float*)d_in[7];
    const float* k_w       = (const float*)d_in[8];
    const float* k_b       = (const float*)d_in[9];
    const float* v_w       = (const float*)d_in[10];
    const float* v_b       = (const float*)d_in[11];
    const float* out_w     = (const float*)d_in[12];
    const float* out_b     = (const float*)d_in[13];
    const float* gammas    = (const float*)d_in[14];
    const float* ln1_g     = (const float*)d_in[15];
    const float* ln1_b     = (const float*)d_in[16];
    const float* ff1_w     = (const float*)d_in[17];
    const float* ff1_b     = (const float*)d_in[18];
    const float* ff2_w     = (const float*)d_in[19];
    const float* ff2_b     = (const float*)d_in[20];
    const float* ln2_g     = (const float*)d_in[21];
    const float* ln2_b     = (const float*)d_in[22];

    const size_t NT = (size_t)M_ * D_;
    float* X = (float*)d_out;
    char* w = (char*)d_ws;
    float* Y  = (float*)w; w += NT * 4;          // 16 MB
    float* Fb = (float*)w; w += NT * 4;          // 16 MB
    u16* Sb = (u16*)w;                           // scores/P bf16: 128 MB
    u16* Hb = Sb;                                // aliases: ffn hidden bf16 (32 MB)
    u16* Xpad = Sb;                              // aliases: prep buffers
    u16* Ypad = Xpad + (size_t)BSZ * TP_ * D_;
    u16* W5t  = Ypad + (size_t)BSZ * TP_ * D_;
    w += (size_t)BSZ * H_ * T_ * T_ * 2;
    u16* Xb  = (u16*)w; w += NT * 2;
    u16* Yb  = (u16*)w; w += NT * 2;
    u16* Cb  = (u16*)w; w += NT * 2;
    u16* Qh  = (u16*)w; w += NT * 2;
    u16* Vt  = (u16*)w; w += NT * 2;
    u16* KWt = (u16*)w; w += (size_t)6 * D_ * D_ * 2;
    u16* VWt = (u16*)w; w += (size_t)6 * D_ * D_ * 2;
    u16* OWt = (u16*)w; w += (size_t)6 * D_ * D_ * 2;
    u16* F1t = (u16*)w; w += (size_t)6 * D_ * FF_ * 2;
    u16* F2t = (u16*)w; w += (size_t)6 * FF_ * D_ * 2;

    dim3 blk(256);

    // ---- prep ----
    cast_pad<<<(BSZ * TP_ * D_ + 255) / 256, blk, 0, stream>>>(q_embed, qa_embed, Xpad, Ypad);
    w5_gather<<<(5 * D_ * D_ + 255) / 256, blk, 0, stream>>>(conv_w, W5t);
    transpose_bf16<<<dim3(D_ / 32, D_ / 32, 6), blk, 0, stream>>>(k_w, KWt, D_, D_);
    transpose_bf16<<<dim3(D_ / 32, D_ / 32, 6), blk, 0, stream>>>(v_w, VWt, D_, D_);
    transpose_bf16<<<dim3(D_ / 32, D_ / 32, 6), blk, 0, stream>>>(out_w, OWt, D_, D_);
    transpose_bf16<<<dim3(FF_ / 32, D_ / 32, 6), blk, 0, stream>>>(ff1_w, F1t, D_, FF_);
    transpose_bf16<<<dim3(D_ / 32, FF_ / 32, 6), blk, 0, stream>>>(ff2_w, F2t, FF_, D_);

    // ---- smooth(x), smooth(y) ----  (64-tile conv: 1024 blocks = 4/CU)
    conv64_mfma<<<dim3(8, 128), blk, 0, stream>>>(Xpad, W5t, Fb);
    smooth_ln<<<M_, blk, 0, stream>>>(q_embed, Fb, conv_b, sqrt_beta, sm_g, sm_b, X, Xb);
    conv64_mfma<<<dim3(8, 128), blk, 0, stream>>>(Ypad, W5t, Fb);
    smooth_ln<<<M_, blk, 0, stream>>>(qa_embed, Fb, conv_b, sqrt_beta, sm_g, sm_b, Y, Yb);

    auto layer = [&](int l, int mtype, float* io, u16* iob, const u16* vinb, bool ffn) {
        gemm64_mfma<<<dim3(8, 128), blk, 0, stream>>>(iob, KWt + (size_t)l * D_ * D_,
                                                      k_b + (size_t)l * D_, Qh, D_, D_, 2);
        gemm64_mfma<<<dim3(8, 128), blk, 0, stream>>>(vinb, VWt + (size_t)l * D_ * D_,
                                                      v_b + (size_t)l * D_, Vt, D_, D_, 3);
        qk_mfma<<<dim3(16, 16, 64), blk, 0, stream>>>(Qh, Sb);
        decay_rows<<<dim3(T_ / 4, 64), blk, 0, stream>>>(Sb, gammas + l * H_, mtype);
        pv_mfma<<<dim3(16, 64), blk, 0, stream>>>(Sb, Vt, Cb);
        gemm64_mfma<<<dim3(8, 128), blk, 0, stream>>>(Cb, OWt + (size_t)l * D_ * D_,
                                                      out_b + (size_t)l * D_, Fb, D_, D_, 0);
        add_ln<<<M_, blk, 0, stream>>>(io, Fb, ln1_g + l * D_, ln1_b + l * D_, io, iob, 1e-5f);
        if (ffn) {
            gemm_mfma<<<dim3(16, 64), blk, 0, stream>>>(iob, F1t + (size_t)l * D_ * FF_,
                                                        ff1_b + (size_t)l * FF_, Hb, FF_, D_, 1);
            gemm64_mfma<<<dim3(8, 128), blk, 0, stream>>>(Hb, F2t + (size_t)l * FF_ * D_,
                                                          ff2_b + (size_t)l * D_, Fb, D_, FF_, 0);
            add_ln<<<M_, blk, 0, stream>>>(io, Fb, ln2_g + l * D_, ln2_b + l * D_, io, iob, 1e-5f);
        }
    };

    layer(0, 1, Y, Yb, Yb, true);
    layer(1, 1, Y, Yb, Yb, true);
    layer(2, 1, X, Xb, Xb, false);
    layer(3, 0, X, Xb, Yb, true);
    layer(4, 1, X, Xb, Xb, false);
    layer(5, 0, X, Xb, Yb, true);
}

// Round 8
// 1693.720 us; speedup vs baseline: 1.3290x; 1.0364x over previous
//
#include <hip/hip_runtime.h>
#include <math.h>

#define T_  1024
#define D_  512
#define H_  8
#define DK_ 64
#define FF_ 2048
#define BSZ 8
#define M_  (BSZ * T_)   // 8192 rows
#define TP_ (T_ + 4)     // padded rows per batch for causal conv

typedef unsigned short u16;
typedef unsigned int u32;
typedef __attribute__((ext_vector_type(8))) __bf16 bf16x8;
typedef __attribute__((ext_vector_type(4))) float f32x4;

__device__ __forceinline__ u16 f2bf(float f) {            // RNE f32 -> bf16 bits
    unsigned int u = __float_as_uint(f);
    u += 0x7fffu + ((u >> 16) & 1u);
    return (u16)(u >> 16);
}
__device__ __forceinline__ float bf2f(u16 b) {
    return __uint_as_float((unsigned int)b << 16);
}

__device__ __forceinline__ void gload16(const void* g, void* l) {
    // async global->LDS, 16B/lane; LDS dest = wave-uniform base + lane*16
    __builtin_amdgcn_global_load_lds(
        (const __attribute__((address_space(1))) void*)g,
        (__attribute__((address_space(3))) void*)l, 16, 0, 0);
}

// ======================= bf16 MFMA GEMM (m97 structure) =======================
// C[M][N] = A[M][K](bf16) * Bt[N][K]^T(bf16) + bias. 128x128 tile, 4 waves.
// Used for FFN1 (M=8192, N=2048) where the grid is already 1024 blocks.
__global__ void __launch_bounds__(256) gemm_mfma(
    const u16* __restrict__ A, const u16* __restrict__ Bt,
    const float* __restrict__ bias, void* __restrict__ Cout,
    int N, int K, int mode)
{
    __shared__ __align__(16) u16 As[128 * 32];
    __shared__ __align__(16) u16 Bs[128 * 32];
    int tid = threadIdx.x;
    int wid = tid >> 6, lane = tid & 63;
    int quad = lane >> 4, mrow = lane & 15;
    int m0 = blockIdx.y * 128, n0 = blockIdx.x * 128;
    int wr = (wid >> 1) * 64, wc = (wid & 1) * 64;

    const u16* Ap = A + (size_t)(m0 + (tid >> 2)) * K + (tid & 3) * 8;
    const u16* Bp = Bt + (size_t)(n0 + (tid >> 2)) * K + (tid & 3) * 8;
    char* lA = (char*)As + wid * 1024;
    char* lB = (char*)Bs + wid * 1024;

    f32x4 acc[4][4] = {};
    for (int k0 = 0; k0 < K; k0 += 32) {
        __syncthreads();
        gload16(Ap + k0, lA);
        gload16(Ap + (size_t)64 * K + k0, lA + 4096);
        gload16(Bp + k0, lB);
        gload16(Bp + (size_t)64 * K + k0, lB + 4096);
        asm volatile("s_waitcnt vmcnt(0)" ::: "memory");
        __syncthreads();
        bf16x8 af[4], bf[4];
#pragma unroll
        for (int t = 0; t < 4; ++t) {
            af[t] = *(const bf16x8*)&As[(wr + t * 16 + mrow) * 32 + quad * 8];
            bf[t] = *(const bf16x8*)&Bs[(wc + t * 16 + mrow) * 32 + quad * 8];
        }
#pragma unroll
        for (int rt = 0; rt < 4; ++rt)
#pragma unroll
            for (int ct = 0; ct < 4; ++ct)
                acc[rt][ct] = __builtin_amdgcn_mfma_f32_16x16x32_bf16(
                    af[rt], bf[ct], acc[rt][ct], 0, 0, 0);
    }

#pragma unroll
    for (int ct = 0; ct < 4; ++ct) {
        int col = n0 + wc + ct * 16 + mrow;
        float bv = bias ? bias[col] : 0.f;
#pragma unroll
        for (int rt = 0; rt < 4; ++rt) {
            int rowb = m0 + wr + rt * 16 + quad * 4;
            if (mode == 0) {
                float* C = (float*)Cout;
#pragma unroll
                for (int e = 0; e < 4; ++e)
                    C[(size_t)(rowb + e) * N + col] = acc[rt][ct][e] + bv;
            } else if (mode == 1) {
                u16* C = (u16*)Cout;
#pragma unroll
                for (int e = 0; e < 4; ++e)
                    C[(size_t)(rowb + e) * N + col] = f2bf(fmaxf(acc[rt][ct][e] + bv, 0.f));
            } else {
                u16* C = (u16*)Cout;
#pragma unroll
                for (int e = 0; e < 4; ++e)
                    C[(size_t)(rowb + e) * N + col] = f2bf(acc[rt][ct][e] + bv);
            }
        }
    }
}

// ======================= bf16 MFMA GEMM, 64x64 tile, BK=64 K-steps ===================
// Grid (N/64, M/64) -> 1024+ blocks = 4+ blocks/CU. LDS = two 64x32 sub-tiles per
// operand (identical ds_read pattern to the proven 32-step kernel: 0 bank conflicts),
// but ONE barrier+vmcnt(0) drain per 64 K-elements instead of two.
// modes: 0 f32; 1 bf16 relu; 2 bf16; 3 per-head-transposed bf16 Vt.
__global__ void __launch_bounds__(256) gemm64_mfma(
    const u16* __restrict__ A, const u16* __restrict__ Bt,
    const float* __restrict__ bias, void* __restrict__ Cout,
    int N, int K, int mode)
{
    __shared__ __align__(16) u16 As[2 * 64 * 32];
    __shared__ __align__(16) u16 Bs[2 * 64 * 32];
    int tid = threadIdx.x;
    int wid = tid >> 6, lane = tid & 63;
    int quad = lane >> 4, mrow = lane & 15;
    int m0 = blockIdx.y * 64, n0 = blockIdx.x * 64;
    int wc = wid * 16;

    const u16* Ap = A + (size_t)(m0 + (tid >> 2)) * K + (tid & 3) * 8;
    const u16* Bp = Bt + (size_t)(n0 + (tid >> 2)) * K + (tid & 3) * 8;
    char* lA = (char*)As + wid * 1024;
    char* lB = (char*)Bs + wid * 1024;

    f32x4 acc[4] = {};
    for (int k0 = 0; k0 < K; k0 += 64) {
        __syncthreads();
        gload16(Ap + k0, lA);
        gload16(Ap + k0 + 32, lA + 4096);
        gload16(Bp + k0, lB);
        gload16(Bp + k0 + 32, lB + 4096);
        asm volatile("s_waitcnt vmcnt(0)" ::: "memory");
        __syncthreads();
#pragma unroll
        for (int q = 0; q < 2; ++q) {
            bf16x8 af[4];
#pragma unroll
            for (int t = 0; t < 4; ++t)
                af[t] = *(const bf16x8*)&As[q * 2048 + (t * 16 + mrow) * 32 + quad * 8];
            bf16x8 bf = *(const bf16x8*)&Bs[q * 2048 + (wc + mrow) * 32 + quad * 8];
#pragma unroll
            for (int rt = 0; rt < 4; ++rt)
                acc[rt] = __builtin_amdgcn_mfma_f32_16x16x32_bf16(af[rt], bf, acc[rt], 0, 0, 0);
        }
    }

    int col = n0 + wc + mrow;
    float bv = bias ? bias[col] : 0.f;
#pragma unroll
    for (int rt = 0; rt < 4; ++rt) {
        int rowb = m0 + rt * 16 + quad * 4;
        if (mode == 0) {
            float* C = (float*)Cout;
#pragma unroll
            for (int e = 0; e < 4; ++e)
                C[(size_t)(rowb + e) * N + col] = acc[rt][e] + bv;
        } else if (mode == 1) {
            u16* C = (u16*)Cout;
#pragma unroll
            for (int e = 0; e < 4; ++e)
                C[(size_t)(rowb + e) * N + col] = f2bf(fmaxf(acc[rt][e] + bv, 0.f));
        } else if (mode == 2) {
            u16* C = (u16*)Cout;
#pragma unroll
            for (int e = 0; e < 4; ++e)
                C[(size_t)(rowb + e) * N + col] = f2bf(acc[rt][e] + bv);
        } else {
            u16* C = (u16*)Cout;
            int h = col >> 6, dl = col & 63;
#pragma unroll
            for (int e = 0; e < 4; ++e) {
                int row = rowb + e;
                int b = row >> 10, t = row & (T_ - 1);
                C[(((size_t)(b * H_ + h) * DK_ + dl) << 10) + t] =
                    f2bf(acc[rt][e] + bv);
            }
        }
    }
}

// ======================= causal conv1d: 5 shifted passes, 64x64 tile, BK=64 =========
__global__ void __launch_bounds__(256) conv64_mfma(
    const u16* __restrict__ Xp, const u16* __restrict__ W5t, float* __restrict__ C)
{
    __shared__ __align__(16) u16 As[2 * 64 * 32];
    __shared__ __align__(16) u16 Bs[2 * 64 * 32];
    int tid = threadIdx.x;
    int wid = tid >> 6, lane = tid & 63;
    int quad = lane >> 4, mrow = lane & 15;
    int m0 = blockIdx.y * 64, n0 = blockIdx.x * 64;
    int wc = wid * 16;
    int b = m0 >> 10, tloc = m0 & (T_ - 1);

    const u16* Ap0 = Xp + (size_t)(b * TP_ + tloc + (tid >> 2)) * D_ + (tid & 3) * 8;
    const u16* Bp0 = W5t + (size_t)(n0 + (tid >> 2)) * D_ + (tid & 3) * 8;
    char* lA = (char*)As + wid * 1024;
    char* lB = (char*)Bs + wid * 1024;

    // 40 steps of BK=64: step s -> ks = s>>3, k0 = (s&7)*64
    f32x4 acc[4] = {};
    for (int s = 0; s < 40; ++s) {
        int ks = s >> 3, k0 = (s & 7) * 64;
        const u16* Ap = Ap0 + ks * D_ + k0;
        const u16* Bp = Bp0 + (size_t)ks * D_ * D_ + k0;
        __syncthreads();
        gload16(Ap, lA);
        gload16(Ap + 32, lA + 4096);
        gload16(Bp, lB);
        gload16(Bp + 32, lB + 4096);
        asm volatile("s_waitcnt vmcnt(0)" ::: "memory");
        __syncthreads();
#pragma unroll
        for (int q = 0; q < 2; ++q) {
            bf16x8 af[4];
#pragma unroll
            for (int t = 0; t < 4; ++t)
                af[t] = *(const bf16x8*)&As[q * 2048 + (t * 16 + mrow) * 32 + quad * 8];
            bf16x8 bf = *(const bf16x8*)&Bs[q * 2048 + (wc + mrow) * 32 + quad * 8];
#pragma unroll
            for (int rt = 0; rt < 4; ++rt)
                acc[rt] = __builtin_amdgcn_mfma_f32_16x16x32_bf16(af[rt], bf, acc[rt], 0, 0, 0);
        }
    }
    int col = n0 + wc + mrow;
#pragma unroll
    for (int rt = 0; rt < 4; ++rt) {
        int row = m0 + rt * 16 + quad * 4;
#pragma unroll
        for (int e = 0; e < 4; ++e)
            C[(size_t)(row + e) * D_ + col] = acc[rt][e];
    }
}

// ======================= QK^T MFMA: single-stage (DK=64), ONE barrier ================
__global__ void __launch_bounds__(256) qk_mfma(
    const u16* __restrict__ Qh, u16* __restrict__ S)
{
    int kt = blockIdx.x, it = blockIdx.y;
    if (kt > it) return;
    int z = blockIdx.z;
    int b = z >> 3, h = z & 7;
    __shared__ __align__(16) u16 As[2 * 64 * 32];
    __shared__ __align__(16) u16 Bs[2 * 64 * 32];
    int tid = threadIdx.x;
    int wid = tid >> 6, lane = tid & 63;
    int quad = lane >> 4, mrow = lane & 15;
    int wc = wid * 16;

    const u16* Ap = Qh + (size_t)(b * T_ + it * 64 + (tid >> 2)) * D_ + h * DK_ + (tid & 3) * 8;
    const u16* Bp = Qh + (size_t)(b * T_ + kt * 64 + (tid >> 2)) * D_ + h * DK_ + (tid & 3) * 8;
    char* lA = (char*)As + wid * 1024;
    char* lB = (char*)Bs + wid * 1024;

    gload16(Ap, lA);
    gload16(Ap + 32, lA + 4096);
    gload16(Bp, lB);
    gload16(Bp + 32, lB + 4096);
    asm volatile("s_waitcnt vmcnt(0)" ::: "memory");
    __syncthreads();

    f32x4 acc[4] = {};
#pragma unroll
    for (int q = 0; q < 2; ++q) {
        bf16x8 af[4];
#pragma unroll
        for (int t = 0; t < 4; ++t)
            af[t] = *(const bf16x8*)&As[q * 2048 + (t * 16 + mrow) * 32 + quad * 8];
        bf16x8 bf = *(const bf16x8*)&Bs[q * 2048 + (wc + mrow) * 32 + quad * 8];
#pragma unroll
        for (int rt = 0; rt < 4; ++rt)
            acc[rt] = __builtin_amdgcn_mfma_f32_16x16x32_bf16(af[rt], bf, acc[rt], 0, 0, 0);
    }
    int col = kt * 64 + wc + mrow;
#pragma unroll
    for (int rt = 0; rt < 4; ++rt) {
        int row = it * 64 + rt * 16 + quad * 4;
#pragma unroll
        for (int e = 0; e < 4; ++e)
            S[((size_t)z * T_ + row + e) * T_ + col] = f2bf(acc[rt][e] * 0.125f);
    }
}

// ======================= per-row decay + double softmax, one WAVE per row ==========
// template<NC> fully-unrolled bodies dispatched on wave-uniform nc (R7: 68us).
#define LOG2E 1.4426950408889634f

// update_dpp: lanes with invalid source get OLDB (identity).
#define DPPF(OLDB, X, CTRL, RM) \
    __uint_as_float((u32)__builtin_amdgcn_update_dpp( \
        (int)(OLDB), __float_as_int(X), CTRL, RM, 0xf, false))

__device__ __forceinline__ float scan_add_f(float x) {   // inclusive 64-lane prefix sum
    x += DPPF(0u, x, 0x111, 0xf);   // row_shr:1
    x += DPPF(0u, x, 0x112, 0xf);   // row_shr:2
    x += DPPF(0u, x, 0x114, 0xf);   // row_shr:4
    x += DPPF(0u, x, 0x118, 0xf);   // row_shr:8
    x += DPPF(0u, x, 0x142, 0xa);   // row_bcast:15 -> rows 1,3
    x += DPPF(0u, x, 0x143, 0xc);   // row_bcast:31 -> rows 2,3
    return x;
}
__device__ __forceinline__ float scan_max_f(float x) {   // inclusive 64-lane prefix max
    x = fmaxf(x, DPPF(0xff800000u, x, 0x111, 0xf));
    x = fmaxf(x, DPPF(0xff800000u, x, 0x112, 0xf));
    x = fmaxf(x, DPPF(0xff800000u, x, 0x114, 0xf));
    x = fmaxf(x, DPPF(0xff800000u, x, 0x118, 0xf));
    x = fmaxf(x, DPPF(0xff800000u, x, 0x142, 0xa));
    x = fmaxf(x, DPPF(0xff800000u, x, 0x143, 0xc));
    return x;
}
__device__ __forceinline__ float lane63(float x) {       // broadcast lane 63 (uniform)
    return __uint_as_float((u32)__builtin_amdgcn_readlane(__float_as_int(x), 63));
}

template<int NC>
__device__ __forceinline__ void decay_body(
    u16* __restrict__ row, int kmax, float gam, float fi, int lane, int wend)
{
    int base = lane * 2;
    float s0[NC], s1[NC], p0[NC], p1[NC];

    // ---- pass 1: load (log2e-scaled), mask boundary chunk, wave max ----
    float mx = -1e30f;
#pragma unroll
    for (int c = 0; c < NC; ++c) {
        int k = c * 128 + base;
        u32 v = *(const u32*)(row + k);
        float a = __uint_as_float(v << 16) * LOG2E;
        float b = __uint_as_float(v & 0xffff0000u) * LOG2E;
        if (c == NC - 1) {              // chunks < NC-1 are provably all <= kmax
            a = (k     <= kmax) ? a : -1.5e30f;
            b = (k + 1 <= kmax) ? b : -1.5e30f;
        }
        s0[c] = a; s1[c] = b;
        mx = fmaxf(mx, fmaxf(a, b));
    }
    mx = lane63(scan_max_f(mx));

    // ---- pass 2: softmax#1 exps (unnormalized; masked -> underflow 0) ----
    float t1 = 0.f;
#pragma unroll
    for (int c = 0; c < NC; ++c) {
        float e0 = __builtin_amdgcn_exp2f(s0[c] - mx);
        float e1 = __builtin_amdgcn_exp2f(s1[c] - mx);
        p0[c] = e0; p1[c] = e1;
        t1 += e0 + e1;
    }
    float tot = lane63(scan_add_f(t1));
    float inv1 = __builtin_amdgcn_rcpf(tot);
    float mx2 = fmaxf(mx, 0.f);         // bound: eff<=1 => s*eff <= max(mx,0)

    // ---- pass 3 (fused): cumsum scan + distance effect + softmax#2 exp ----
    float t2 = 0.f;
    float running = 0.f;
    float kf = (float)base;
#pragma unroll
    for (int c = 0; c < NC; ++c) {
        float sc = scan_add_f(p0[c] + p1[c]);
        float incl1 = running + sc;
        float incl0 = incl1 - p1[c];
        running += lane63(sc);
        float rem0 = fmaxf((tot - incl0) * inv1, 0.f);
        float rem1 = fmaxf((tot - incl1) * inv1, 0.f);
        float pos0 = fabsf(kf - fi);
        float pos1 = fabsf(kf + 1.f - fi);
        float ef0 = __builtin_amdgcn_fmed3f(
            __builtin_amdgcn_exp2f(sqrtf(rem0 * pos0) * gam), 1e-5f, 1e5f);
        float ef1 = __builtin_amdgcn_fmed3f(
            __builtin_amdgcn_exp2f(sqrtf(rem1 * pos1) * gam), 1e-5f, 1e5f);
        // masked: s = -1.5e30, s*ef <= -1.5e25 -> exp2 underflows to 0
        float e0 = __builtin_amdgcn_exp2f(s0[c] * ef0 - mx2);
        float e1 = __builtin_amdgcn_exp2f(s1[c] * ef1 - mx2);
        p0[c] = e0; p1[c] = e1;
        t2 += e0 + e1;
        kf += 128.f;
    }
    float inv2 = __builtin_amdgcn_rcpf(lane63(scan_add_f(t2)));

    // ---- pass 4: write P (v_cvt_pk_bf16_f32), zero-fill tail PV reads ----
#pragma unroll
    for (int c = 0; c < NC; ++c) {
        float lo = p0[c] * inv2, hi = p1[c] * inv2;
        u32 o;
        asm("v_cvt_pk_bf16_f32 %0, %1, %2" : "=v"(o) : "v"(lo), "v"(hi));
        *(u32*)(row + c * 128 + base) = o;
    }
    for (int c = NC; c < wend; ++c)
        *(u32*)(row + c * 128 + base) = 0u;
}

__global__ void __launch_bounds__(256) decay_rows(
    u16* __restrict__ S, const float* __restrict__ gam_l, int mtype)
{
    int tid = threadIdx.x;
    int wv = tid >> 6, lane = tid & 63;
    int i = blockIdx.x * 4 + wv;
    int z = blockIdx.y;
    int h = z & 7;
    u16* row = S + ((size_t)z * T_ + i) * T_;
    int kmax = (mtype == 0) ? (i - 1) : i;

    if (kmax < 0) {                     // mtype==0, i==0 (zero_pad row); PV reads k<64
        row[lane] = 0;
        return;
    }
    int nc   = (kmax >> 7) + 1;         // active 128-wide chunks (1..8), wave-uniform
    int wend = (((i >> 6) + 1) * 64 + 127) >> 7;  // chunks PV reads (zero-fill to here)
    float gam = -log1pf(__expf(gam_l[h])) * LOG2E;
    float fi = (float)i;

    switch (nc) {
        case 1: decay_body<1>(row, kmax, gam, fi, lane, wend); break;
        case 2: decay_body<2>(row, kmax, gam, fi, lane, wend); break;
        case 3: decay_body<3>(row, kmax, gam, fi, lane, wend); break;
        case 4: decay_body<4>(row, kmax, gam, fi, lane, wend); break;
        case 5: decay_body<5>(row, kmax, gam, fi, lane, wend); break;
        case 6: decay_body<6>(row, kmax, gam, fi, lane, wend); break;
        case 7: decay_body<7>(row, kmax, gam, fi, lane, wend); break;
        default: decay_body<8>(row, kmax, gam, fi, lane, wend); break;
    }
}

// ======================= PV MFMA: O = P(bf16) x V, causal K-bound, BK=64 =============
__global__ void __launch_bounds__(256) pv_mfma(
    const u16* __restrict__ P, const u16* __restrict__ Vt,
    u16* __restrict__ O)
{
    int mt = blockIdx.x;
    int z = blockIdx.y;
    int b = z >> 3, h = z & 7;
    __shared__ __align__(16) u16 As[2 * 64 * 32];
    __shared__ __align__(16) u16 Bs[2 * 64 * 32];
    int tid = threadIdx.x;
    int wid = tid >> 6, lane = tid & 63;
    int quad = lane >> 4, mrow = lane & 15;
    int wc = wid * 16;

    const u16* Ap = P + ((size_t)z * T_ + mt * 64 + (tid >> 2)) * T_ + (tid & 3) * 8;
    const u16* Bp = Vt + ((size_t)z * DK_ + (tid >> 2)) * T_ + (tid & 3) * 8;
    char* lA = (char*)As + wid * 1024;
    char* lB = (char*)Bs + wid * 1024;

    int kend = (mt + 1) * 64;           // multiple of 64
    f32x4 acc[4] = {};
    for (int k0 = 0; k0 < kend; k0 += 64) {
        __syncthreads();
        gload16(Ap + k0, lA);
        gload16(Ap + k0 + 32, lA + 4096);
        gload16(Bp + k0, lB);
        gload16(Bp + k0 + 32, lB + 4096);
        asm volatile("s_waitcnt vmcnt(0)" ::: "memory");
        __syncthreads();
#pragma unroll
        for (int q = 0; q < 2; ++q) {
            bf16x8 af[4];
#pragma unroll
            for (int t = 0; t < 4; ++t)
                af[t] = *(const bf16x8*)&As[q * 2048 + (t * 16 + mrow) * 32 + quad * 8];
            bf16x8 bf = *(const bf16x8*)&Bs[q * 2048 + (wc + mrow) * 32 + quad * 8];
#pragma unroll
            for (int rt = 0; rt < 4; ++rt)
                acc[rt] = __builtin_amdgcn_mfma_f32_16x16x32_bf16(af[rt], bf, acc[rt], 0, 0, 0);
        }
    }
    int col = h * DK_ + wc + mrow;
#pragma unroll
    for (int rt = 0; rt < 4; ++rt) {
        int row = b * T_ + mt * 64 + rt * 16 + quad * 4;
#pragma unroll
        for (int e = 0; e < 4; ++e)
            O[(size_t)(row + e) * D_ + col] = f2bf(acc[rt][e]);
    }
}

// ======================= prep kernels =======================
__global__ void __launch_bounds__(256) transpose_bf16(
    const float* __restrict__ W, u16* __restrict__ Wt, int K, int N)
{
    __shared__ float tile[32][33];
    size_t base = (size_t)blockIdx.z * K * N;
    W += base; Wt += base;
    int k0 = blockIdx.y * 32, n0 = blockIdx.x * 32;
    int r = threadIdx.x >> 3, c = (threadIdx.x & 7) * 4;
    float4 v = *(const float4*)(W + (size_t)(k0 + r) * N + n0 + c);
    tile[r][c] = v.x; tile[r][c + 1] = v.y; tile[r][c + 2] = v.z; tile[r][c + 3] = v.w;
    __syncthreads();
    ushort4 o;
    o.x = f2bf(tile[c + 0][r]); o.y = f2bf(tile[c + 1][r]);
    o.z = f2bf(tile[c + 2][r]); o.w = f2bf(tile[c + 3][r]);
    *(ushort4*)(Wt + (size_t)(n0 + r) * K + k0 + c) = o;
}

__global__ void w5_gather(const float* __restrict__ cw, u16* __restrict__ W5t)
{
    int idx = blockIdx.x * 256 + threadIdx.x;
    if (idx >= 5 * D_ * D_) return;
    int ks = idx / (D_ * D_);
    int rem = idx - ks * (D_ * D_);
    int o = rem >> 9, i = rem & (D_ - 1);
    W5t[idx] = f2bf(cw[((size_t)o * D_ + i) * 5 + ks]);
}

__global__ void cast_pad(const float* __restrict__ x, const float* __restrict__ y,
                         u16* __restrict__ Xp, u16* __restrict__ Yp)
{
    int idx = blockIdx.x * 256 + threadIdx.x;
    if (idx >= BSZ * TP_ * D_) return;
    int d = idx & (D_ - 1);
    int rowp = idx >> 9;
    int b = rowp / TP_;
    int t = rowp - b * TP_;
    u16 vx = 0, vy = 0;
    if (t >= 4) {
        size_t src = ((size_t)(b * T_ + t - 4) << 9) + d;
        vx = f2bf(x[src]); vy = f2bf(y[src]);
    }
    Xp[idx] = vx; Yp[idx] = vy;
}

// ======================= smooth pointwise + LayerNorm (eps=1e-12) =======================
__global__ void __launch_bounds__(256) smooth_ln(
    const float* __restrict__ x, const float* __restrict__ trend,
    const float* __restrict__ conv_b, const float* __restrict__ sqrt_beta,
    const float* __restrict__ g, const float* __restrict__ bb,
    float* __restrict__ out, u16* __restrict__ outb)
{
    __shared__ float s_red[8];
    int row = blockIdx.x, tid = threadIdx.x;
    int lane = tid & 63, wid = tid >> 6;
    float2 xv = ((const float2*)(x + (size_t)row * D_))[tid];
    float2 tv = ((const float2*)(trend + (size_t)row * D_))[tid];
    float2 cb = ((const float2*)conv_b)[tid];
    float2 sb = ((const float2*)sqrt_beta)[tid];
    float t0 = tv.x + cb.x, t1 = tv.y + cb.y;
    float v0 = t0 + sb.x * sb.x * (xv.x - t0) + xv.x;
    float v1 = t1 + sb.y * sb.y * (xv.y - t1) + xv.y;
    float s = v0 + v1, sq = v0 * v0 + v1 * v1;
    for (int o = 32; o > 0; o >>= 1) { s += __shfl_xor(s, o, 64); sq += __shfl_xor(sq, o, 64); }
    if (lane == 0) { s_red[wid] = s; s_red[4 + wid] = sq; }
    __syncthreads();
    s = s_red[0] + s_red[1] + s_red[2] + s_red[3];
    sq = s_red[4] + s_red[5] + s_red[6] + s_red[7];
    float mean = s * (1.f / D_);
    float var = sq * (1.f / D_) - mean * mean;
    if (var < 0.f) var = 0.f;
    float rstd = rsqrtf(var + 1e-12f);
    float2 gv = ((const float2*)g)[tid];
    float2 bv = ((const float2*)bb)[tid];
    float2 o2;
    o2.x = gv.x * (v0 - mean) * rstd + bv.x;
    o2.y = gv.y * (v1 - mean) * rstd + bv.y;
    ((float2*)(out + (size_t)row * D_))[tid] = o2;
    ushort2 ob; ob.x = f2bf(o2.x); ob.y = f2bf(o2.y);
    ((ushort2*)(outb + (size_t)row * D_))[tid] = ob;
}

// ======================= residual add + LayerNorm (f32 + bf16 out) =======================
__global__ void __launch_bounds__(256) add_ln(
    const float* __restrict__ a, const float* __restrict__ c,
    const float* __restrict__ g, const float* __restrict__ bb,
    float* __restrict__ out, u16* __restrict__ outb, float eps)
{
    __shared__ float s_red[8];
    int row = blockIdx.x, tid = threadIdx.x;
    int lane = tid & 63, wid = tid >> 6;
    float2 av = ((const float2*)(a + (size_t)row * D_))[tid];
    float2 cv = ((const float2*)(c + (size_t)row * D_))[tid];
    float v0 = av.x + cv.x;
    float v1 = av.y + cv.y;
    float s = v0 + v1, sq = v0 * v0 + v1 * v1;
    for (int o = 32; o > 0; o >>= 1) { s += __shfl_xor(s, o, 64); sq += __shfl_xor(sq, o, 64); }
    if (lane == 0) { s_red[wid] = s; s_red[4 + wid] = sq; }
    __syncthreads();
    s = s_red[0] + s_red[1] + s_red[2] + s_red[3];
    sq = s_red[4] + s_red[5] + s_red[6] + s_red[7];
    float mean = s * (1.f / D_);
    float var = sq * (1.f / D_) - mean * mean;
    if (var < 0.f) var = 0.f;
    float rstd = rsqrtf(var + eps);
    float2 gv = ((const float2*)g)[tid];
    float2 bv = ((const float2*)bb)[tid];
    float2 o2;
    o2.x = gv.x * (v0 - mean) * rstd + bv.x;
    o2.y = gv.y * (v1 - mean) * rstd + bv.y;
    ((float2*)(out + (size_t)row * D_))[tid] = o2;
    ushort2 ob; ob.x = f2bf(o2.x); ob.y = f2bf(o2.y);
    ((ushort2*)(outb + (size_t)row * D_))[tid] = ob;
}

// ======================= launch =======================
extern "C" void kernel_launch(void* const* d_in, const int* in_sizes, int n_in,
                              void* d_out, int out_size, void* d_ws, size_t ws_size,
                              hipStream_t stream)
{
    const float* q_embed   = (const float*)d_in[0];
    const float* qa_embed  = (const float*)d_in[1];
    const float* conv_w    = (const float*)d_in[3];
    const float* conv_b    = (const float*)d_in[4];
    const float* sqrt_beta = (const float*)d_in[5];
    const float* sm_g      = (const float*)d_in[6];
    const float* sm_b      = (const float*)d_in[7];
    const float* k_w       = (const float*)d_in[8];
    const float* k_b       = (const float*)d_in[9];
    const float* v_w       = (const float*)d_in[10];
    const float* v_b       = (const float*)d_in[11];
    const float* out_w     = (const float*)d_in[12];
    const float* out_b     = (const float*)d_in[13];
    const float* gammas    = (const float*)d_in[14];
    const float* ln1_g     = (const float*)d_in[15];
    const float* ln1_b     = (const float*)d_in[16];
    const float* ff1_w     = (const float*)d_in[17];
    const float* ff1_b     = (const float*)d_in[18];
    const float* ff2_w     = (const float*)d_in[19];
    const float* ff2_b     = (const float*)d_in[20];
    const float* ln2_g     = (const float*)d_in[21];
    const float* ln2_b     = (const float*)d_in[22];

    const size_t NT = (size_t)M_ * D_;
    float* X = (float*)d_out;
    char* w = (char*)d_ws;
    float* Y  = (float*)w; w += NT * 4;          // 16 MB
    float* Fb = (float*)w; w += NT * 4;          // 16 MB
    u16* Sb = (u16*)w;                           // scores/P bf16: 128 MB
    u16* Hb = Sb;                                // aliases: ffn hidden bf16 (32 MB)
    u16* Xpad = Sb;                              // aliases: prep buffers
    u16* Ypad = Xpad + (size_t)BSZ * TP_ * D_;
    u16* W5t  = Ypad + (size_t)BSZ * TP_ * D_;
    w += (size_t)BSZ * H_ * T_ * T_ * 2;
    u16* Xb  = (u16*)w; w += NT * 2;
    u16* Yb  = (u16*)w; w += NT * 2;
    u16* Cb  = (u16*)w; w += NT * 2;
    u16* Qh  = (u16*)w; w += NT * 2;
    u16* Vt  = (u16*)w; w += NT * 2;
    u16* KWt = (u16*)w; w += (size_t)6 * D_ * D_ * 2;
    u16* VWt = (u16*)w; w += (size_t)6 * D_ * D_ * 2;
    u16* OWt = (u16*)w; w += (size_t)6 * D_ * D_ * 2;
    u16* F1t = (u16*)w; w += (size_t)6 * D_ * FF_ * 2;
    u16* F2t = (u16*)w; w += (size_t)6 * FF_ * D_ * 2;

    dim3 blk(256);

    // ---- prep ----
    cast_pad<<<(BSZ * TP_ * D_ + 255) / 256, blk, 0, stream>>>(q_embed, qa_embed, Xpad, Ypad);
    w5_gather<<<(5 * D_ * D_ + 255) / 256, blk, 0, stream>>>(conv_w, W5t);
    transpose_bf16<<<dim3(D_ / 32, D_ / 32, 6), blk, 0, stream>>>(k_w, KWt, D_, D_);
    transpose_bf16<<<dim3(D_ / 32, D_ / 32, 6), blk, 0, stream>>>(v_w, VWt, D_, D_);
    transpose_bf16<<<dim3(D_ / 32, D_ / 32, 6), blk, 0, stream>>>(out_w, OWt, D_, D_);
    transpose_bf16<<<dim3(FF_ / 32, D_ / 32, 6), blk, 0, stream>>>(ff1_w, F1t, D_, FF_);
    transpose_bf16<<<dim3(D_ / 32, FF_ / 32, 6), blk, 0, stream>>>(ff2_w, F2t, FF_, D_);

    // ---- smooth(x), smooth(y) ----  (64-tile conv: 1024 blocks = 4/CU)
    conv64_mfma<<<dim3(8, 128), blk, 0, stream>>>(Xpad, W5t, Fb);
    smooth_ln<<<M_, blk, 0, stream>>>(q_embed, Fb, conv_b, sqrt_beta, sm_g, sm_b, X, Xb);
    conv64_mfma<<<dim3(8, 128), blk, 0, stream>>>(Ypad, W5t, Fb);
    smooth_ln<<<M_, blk, 0, stream>>>(qa_embed, Fb, conv_b, sqrt_beta, sm_g, sm_b, Y, Yb);

    auto layer = [&](int l, int mtype, float* io, u16* iob, const u16* vinb, bool ffn) {
        gemm64_mfma<<<dim3(8, 128), blk, 0, stream>>>(iob, KWt + (size_t)l * D_ * D_,
                                                      k_b + (size_t)l * D_, Qh, D_, D_, 2);
        gemm64_mfma<<<dim3(8, 128), blk, 0, stream>>>(vinb, VWt + (size_t)l * D_ * D_,
                                                      v_b + (size_t)l * D_, Vt, D_, D_, 3);
        qk_mfma<<<dim3(16, 16, 64), blk, 0, stream>>>(Qh, Sb);
        decay_rows<<<dim3(T_ / 4, 64), blk, 0, stream>>>(Sb, gammas + l * H_, mtype);
        pv_mfma<<<dim3(16, 64), blk, 0, stream>>>(Sb, Vt, Cb);
        gemm64_mfma<<<dim3(8, 128), blk, 0, stream>>>(Cb, OWt + (size_t)l * D_ * D_,
                                                      out_b + (size_t)l * D_, Fb, D_, D_, 0);
        add_ln<<<M_, blk, 0, stream>>>(io, Fb, ln1_g + l * D_, ln1_b + l * D_, io, iob, 1e-5f);
        if (ffn) {
            gemm_mfma<<<dim3(16, 64), blk, 0, stream>>>(iob, F1t + (size_t)l * D_ * FF_,
                                                        ff1_b + (size_t)l * FF_, Hb, FF_, D_, 1);
            gemm64_mfma<<<dim3(8, 128), blk, 0, stream>>>(Hb, F2t + (size_t)l * FF_ * D_,
                                                          ff2_b + (size_t)l * D_, Fb, D_, FF_, 0);
            add_ln<<<M_, blk, 0, stream>>>(io, Fb, ln2_g + l * D_, ln2_b + l * D_, io, iob, 1e-5f);
        }
    };

    layer(0, 1, Y, Yb, Yb, true);
    layer(1, 1, Y, Yb, Yb, true);
    layer(2, 1, X, Xb, Xb, false);
    layer(3, 0, X, Xb, Yb, true);
    layer(4, 1, X, Xb, Xb, false);
    layer(5, 0, X, Xb, Yb, true);
}